// Round 2
// baseline (184.618 us; speedup 1.0000x reference)
//
#include <hip/hip_runtime.h>
#include <hip/hip_bf16.h>

typedef __bf16  bf16x8 __attribute__((ext_vector_type(8)));
typedef float   f32x4  __attribute__((ext_vector_type(4)));

#define DEV __device__ __forceinline__

DEV ushort f2b(float f){
  union { float f; unsigned u; } c; c.f = f;
  unsigned u = c.u;
  unsigned r = (u + 0x7FFFu + ((u >> 16) & 1u)) >> 16;
  return (ushort)r;
}
DEV float b2f(ushort h){
  union { unsigned u; float f; } c; c.u = ((unsigned)h) << 16;
  return c.f;
}
DEV float wredsum(float v){
  #pragma unroll
  for(int o = 32; o > 0; o >>= 1) v += __shfl_xor(v, o, 64);
  return v;
}
DEV float wredmax(float v){
  #pragma unroll
  for(int o = 32; o > 0; o >>= 1) v = fmaxf(v, __shfl_xor(v, o, 64));
  return v;
}
DEV void gload_lds16(const void* g, void* l){
  __builtin_amdgcn_global_load_lds(
      (const __attribute__((address_space(1))) void*)g,
      (__attribute__((address_space(3))) void*)l,
      16, 0, 0);
}
DEV bf16x8 cvt8(float4 a0, float4 a1){
  bf16x8 t;
  t[0]=(__bf16)a0.x; t[1]=(__bf16)a0.y; t[2]=(__bf16)a0.z; t[3]=(__bf16)a0.w;
  t[4]=(__bf16)a1.x; t[5]=(__bf16)a1.y; t[6]=(__bf16)a1.z; t[7]=(__bf16)a1.w;
  return t;
}

// ---------------- prep: W1 f32->bf16, conv_w pad+cvt, conv_b pad --------------
__global__ void prep(const float* __restrict__ W1, const float* __restrict__ CW,
                     const float* __restrict__ CB,
                     ushort* __restrict__ W1b, ushort* __restrict__ CWb,
                     float* __restrict__ CBp){
  int bid = blockIdx.x, tid = threadIdx.x;
  if(bid < 512){
    int i = bid * 256 + tid;          // float4 index, 131072 total
    float4 f = ((const float4*)W1)[i];
    ushort4 o; o.x = f2b(f.x); o.y = f2b(f.y); o.z = f2b(f.z); o.w = f2b(f.w);
    ((ushort4*)W1b)[i] = o;
  } else if(bid < 768){
    int i = (bid - 512) * 256 + tid;  // 0..65535
    int r = i >> 9;
    CWb[i] = (r < 64) ? f2b(CW[i]) : (ushort)0;
  } else {
    if(tid < 128) CBp[tid] = (tid < 64) ? CB[tid] : 0.0f;
  }
}

// ---------------- fc1 GEMM, 128x128 tile, fused X f32->bf16 --------------------
// Upgraded from 64x128: 4x4 fragment wave-tiles (16 MFMA / k-step / wave vs 8),
// halving LDS-read bytes per MFMA (0.5KB+f32A vs ~1KB). Same proven swizzles:
// A (f32) seg^(row&7) on 128-B rows; B (bf16) slot^((row>>1)&3) on 64-B rows,
// both pre-swizzled at the global source, read swizzled (G21).
__global__ __launch_bounds__(256) void gemm_fc1(
    const float* __restrict__ A, const ushort* __restrict__ B,
    const float* __restrict__ bias, float* __restrict__ C)
{
  const int K = 1024, N = 512;
  __shared__ __align__(16) float  Af[2][128 * 32];   // 2 x 16 KB, seg-swizzled
  __shared__ __align__(16) ushort Bs[2][128 * 32];   // 2 x 8 KB, slot-swizzled
  const int tid = threadIdx.x, lane = tid & 63, wid = tid >> 6;
  const int bm0 = blockIdx.x * 128, bn0 = blockIdx.y * 128;
  const int wr = (wid >> 1) * 64, wc = (wid & 1) * 64;

  // A staging: 128 rows x 128 B per k-step; thread -> (row = tid>>3 (+32p), seg = tid&7)
  const int srow = tid >> 3;
  const int sseg = tid & 7;
  const int sswz = sseg ^ (srow & 7);                // (srow+32p)&7 == srow&7
  const char* asrc = (const char*)A + (size_t)(bm0 + srow) * 4096 + sswz * 16;

  // B staging: row = tid>>2 (+64p), slot = tid&3; source slot pre-swizzled
  const int bslot = (tid & 3) ^ ((tid >> 3) & 3);    // ((row+64p)>>1)&3 invariant
  const ushort* bg = B + (size_t)(bn0 + (tid >> 2)) * K + bslot * 8;

  f32x4 acc[4][4];
  #pragma unroll
  for(int i = 0; i < 4; i++)
    #pragma unroll
    for(int j = 0; j < 4; j++) acc[i][j] = (f32x4){0.f, 0.f, 0.f, 0.f};

  const int arow = lane & 15;
  const int khalf = lane >> 4;

#define STAGE_FC1(buf, kb) do { \
    const char* s_ = asrc + (kb); \
    char* d_ = (char*)&Af[buf][0] + srow * 128 + sseg * 16; \
    gload_lds16(s_,             d_); \
    gload_lds16(s_ + 32 * 4096, d_ + 32 * 128); \
    gload_lds16(s_ + 64 * 4096, d_ + 64 * 128); \
    gload_lds16(s_ + 96 * 4096, d_ + 96 * 128); \
    const ushort* bs_ = bg + ((kb) >> 2); \
    gload_lds16(bs_,          &Bs[buf][tid * 8]); \
    gload_lds16(bs_ + 64 * K, &Bs[buf][2048 + tid * 8]); \
  } while(0)

  STAGE_FC1(0, 0);
  __syncthreads();

  int cur = 0;
  for(int ks = 0; ks < 32; ++ks){
    if(ks + 1 < 32) STAGE_FC1(cur ^ 1, (ks + 1) * 128);
    bf16x8 af[4], bfr[4];
    #pragma unroll
    for(int mi = 0; mi < 4; mi++){
      int r = wr + mi * 16 + arow;
      const char* base = (const char*)&Af[cur][0] + r * 128;
      float4 a0 = *(const float4*)(base + (((khalf * 2)     ^ (r & 7)) * 16));
      float4 a1 = *(const float4*)(base + (((khalf * 2 + 1) ^ (r & 7)) * 16));
      af[mi] = cvt8(a0, a1);
    }
    #pragma unroll
    for(int ni = 0; ni < 4; ni++){
      int r = wc + ni * 16 + arow;
      bfr[ni] = *(const bf16x8*)&Bs[cur][r * 32 + ((khalf ^ ((r >> 1) & 3)) * 8)];
    }
    #pragma unroll
    for(int mi = 0; mi < 4; mi++)
      #pragma unroll
      for(int ni = 0; ni < 4; ni++)
        acc[mi][ni] = __builtin_amdgcn_mfma_f32_16x16x32_bf16(af[mi], bfr[ni], acc[mi][ni], 0, 0, 0);
    __syncthreads();
    cur ^= 1;
  }
#undef STAGE_FC1

  const int crow0 = bm0 + wr + (lane >> 4) * 4;
  const int ccol0 = bn0 + wc + (lane & 15);
  #pragma unroll
  for(int mi = 0; mi < 4; mi++)
    #pragma unroll
    for(int ni = 0; ni < 4; ni++){
      int col = ccol0 + ni * 16;
      float bv = bias[col];
      #pragma unroll
      for(int i = 0; i < 4; i++){
        int row = crow0 + mi * 16 + i;
        C[(size_t)row * N + col] = fmaxf(acc[mi][ni][i] + bv, 0.f);
      }
    }
}

// ---------------- bf16 MFMA GEMM (logits), slot-swizzled tiles -----------------
__global__ __launch_bounds__(256) void gemm_bt(
    const ushort* __restrict__ A, const ushort* __restrict__ B,
    const float* __restrict__ bias, float* __restrict__ C,
    int K, int N, int relu)
{
  __shared__ __align__(16) ushort As[2][128*32];
  __shared__ __align__(16) ushort Bs[2][128*32];
  const int tid  = threadIdx.x;
  const int lane = tid & 63, wid = tid >> 6;
  const int bm0 = blockIdx.x * 128, bn0 = blockIdx.y * 128;
  const int wr = (wid >> 1) * 64, wc = (wid & 1) * 64;

  const int slot = (tid & 3) ^ ((tid >> 3) & 3);   // pre-swizzled source slot
  const ushort* ag = A + (size_t)(bm0 + (tid >> 2)) * K + slot * 8;
  const ushort* bg = B + (size_t)(bn0 + (tid >> 2)) * K + slot * 8;

  f32x4 acc[4][4];
  #pragma unroll
  for(int i = 0; i < 4; i++)
    #pragma unroll
    for(int j = 0; j < 4; j++) acc[i][j] = (f32x4){0.f, 0.f, 0.f, 0.f};

  const int arow = lane & 15;
  const int khalf = lane >> 4;
  const int nk = K >> 5;

  gload_lds16(ag,          &As[0][tid * 8]);
  gload_lds16(ag + 64 * K, &As[0][2048 + tid * 8]);
  gload_lds16(bg,          &Bs[0][tid * 8]);
  gload_lds16(bg + 64 * K, &Bs[0][2048 + tid * 8]);
  __syncthreads();

  int cur = 0;
  for(int ks = 0; ks < nk; ++ks){
    if(ks + 1 < nk){
      const ushort* agn = ag + (ks + 1) * 32;
      const ushort* bgn = bg + (ks + 1) * 32;
      gload_lds16(agn,          &As[cur ^ 1][tid * 8]);
      gload_lds16(agn + 64 * K, &As[cur ^ 1][2048 + tid * 8]);
      gload_lds16(bgn,          &Bs[cur ^ 1][tid * 8]);
      gload_lds16(bgn + 64 * K, &Bs[cur ^ 1][2048 + tid * 8]);
    }
    bf16x8 af[4], bfr[4];
    #pragma unroll
    for(int mi = 0; mi < 4; mi++){
      int r = wr + mi * 16 + arow;
      af[mi] = *(const bf16x8*)&As[cur][r * 32 + ((khalf ^ ((r >> 1) & 3)) * 8)];
    }
    #pragma unroll
    for(int ni = 0; ni < 4; ni++){
      int r = wc + ni * 16 + arow;
      bfr[ni] = *(const bf16x8*)&Bs[cur][r * 32 + ((khalf ^ ((r >> 1) & 3)) * 8)];
    }
    #pragma unroll
    for(int mi = 0; mi < 4; mi++)
      #pragma unroll
      for(int ni = 0; ni < 4; ni++)
        acc[mi][ni] = __builtin_amdgcn_mfma_f32_16x16x32_bf16(af[mi], bfr[ni], acc[mi][ni], 0, 0, 0);
    __syncthreads();
    cur ^= 1;
  }

  const int crow0 = bm0 + wr + (lane >> 4) * 4;
  const int ccol0 = bn0 + wc + (lane & 15);
  #pragma unroll
  for(int mi = 0; mi < 4; mi++)
    #pragma unroll
    for(int ni = 0; ni < 4; ni++){
      int col = ccol0 + ni * 16;
      float bv = bias[col];
      #pragma unroll
      for(int i = 0; i < 4; i++){
        int row = crow0 + mi * 16 + i;
        float v = acc[mi][ni][i] + bv;
        if(relu) v = fmaxf(v, 0.f);
        C[(size_t)row * N + col] = v;
      }
    }
}

// ---------------- per-row L2 normalize: h f32 [16384][512] -> xn bf16 ----------
__global__ __launch_bounds__(256) void norm_rows(const float* __restrict__ h, ushort* __restrict__ xn){
  __shared__ float sred[4];
  int row = blockIdx.x;
  int tid = threadIdx.x, lane = tid & 63, wid = tid >> 6;
  const float2 v = *(const float2*)&h[(size_t)row * 512 + tid * 2];
  float ss = v.x * v.x + v.y * v.y;
  ss = wredsum(ss);
  if(lane == 0) sred[wid] = ss;
  __syncthreads();
  float tot = sred[0] + sred[1] + sred[2] + sred[3];
  float sc = 1.0f / fmaxf(sqrtf(tot), 1e-12f);
  ushort2 o; o.x = f2b(v.x * sc); o.y = f2b(v.y * sc);
  *(ushort2*)&xn[(size_t)row * 512 + tid * 2] = o;
}

// ------------- softmax over 64 clusters + transpose to a_t[b][k][n] f32 --------
__global__ __launch_bounds__(256) void softmax_t(const float* __restrict__ logits, float* __restrict__ at){
  __shared__ float as_[64][65];
  int tid = threadIdx.x, lane = tid & 63, wid = tid >> 6;
  int r0 = blockIdx.x * 64;
  int b = r0 >> 10, n0 = r0 & 1023;
  for(int i = 0; i < 16; i++){
    int rl = wid * 16 + i;
    float l = logits[(size_t)(r0 + rl) * 128 + lane];
    float m = wredmax(l);
    float e = __expf(l - m);
    float s = wredsum(e);
    as_[rl][lane] = e / s;
  }
  __syncthreads();
  int nl = tid & 63;
  int kq = tid >> 6;
  for(int q = 0; q < 16; q++){
    int k = kq * 16 + q;
    at[((size_t)b * 64 + k) * 1024 + n0 + nl] = as_[nl][k];
  }
}

// ------------- VLAD aggregate + intra-normalize -> bf16, plus slice sumsq ------
__global__ __launch_bounds__(512) void vlad_k(const float* __restrict__ at, const ushort* __restrict__ xn,
                                              const float* __restrict__ cent,
                                              ushort* __restrict__ vlb, float* __restrict__ ssq){
  __shared__ float a4[4][1024];
  __shared__ float asum_s[4];
  __shared__ float red[8][4];
  __shared__ float scale_s[4];
  __shared__ float ssq_s[4];
  int tid = threadIdx.x, lane = tid & 63, wid = tid >> 6;
  int b = blockIdx.x, k0 = blockIdx.y * 4;
  #pragma unroll
  for(int u = 0; u < 2; u++){
    int idx = tid * 8 + u * 4;
    int j = idx >> 10, n = idx & 1023;
    *(float4*)&a4[j][n] = *(const float4*)&at[((size_t)b * 64 + k0 + j) * 1024 + n];
  }
  __syncthreads();
  if(wid < 4){
    float p = 0;
    for(int t = lane; t < 1024; t += 64) p += a4[wid][t];
    p = wredsum(p);
    if(lane == 0) asum_s[wid] = p;
  }
  __syncthreads();
  int h = tid;
  const ushort* xb = xn + (size_t)b * 1024 * 512 + h;
  float acc[4] = {0, 0, 0, 0};
  for(int n0 = 0; n0 < 1024; n0 += 8){
    float xv[8];
    #pragma unroll
    for(int u = 0; u < 8; u++) xv[u] = b2f(xb[(size_t)(n0 + u) * 512]);
    #pragma unroll
    for(int j = 0; j < 4; j++){
      float4 alo = *(const float4*)&a4[j][n0];
      float4 ahi = *(const float4*)&a4[j][n0 + 4];
      acc[j] += alo.x * xv[0] + alo.y * xv[1] + alo.z * xv[2] + alo.w * xv[3]
              + ahi.x * xv[4] + ahi.y * xv[5] + ahi.z * xv[6] + ahi.w * xv[7];
    }
  }
  float vl[4];
  #pragma unroll
  for(int j = 0; j < 4; j++)
    vl[j] = acc[j] - asum_s[j] * cent[(size_t)(k0 + j) * 512 + h];
  #pragma unroll
  for(int j = 0; j < 4; j++){
    float s = wredsum(vl[j] * vl[j]);
    if(lane == 0) red[wid][j] = s;
  }
  __syncthreads();
  if(tid < 4){
    float s = 0;
    #pragma unroll
    for(int w = 0; w < 8; w++) s += red[w][tid];
    float sc = 1.0f / fmaxf(sqrtf(s), 1e-12f);
    scale_s[tid] = sc;
    ssq_s[tid] = s * sc * sc;
  }
  __syncthreads();
  if(tid == 0) ssq[b * 16 + blockIdx.y] = ssq_s[0] + ssq_s[1] + ssq_s[2] + ssq_s[3];
  #pragma unroll
  for(int j = 0; j < 4; j++)
    vlb[(size_t)b * 32768 + (size_t)(k0 + j) * 512 + h] = f2b(vl[j] * scale_s[j]);
}

// ------------- fc2 via MFMA, dbuf staging, K-split 32 (deep K per block) -------
// K-split reduced 128->32: fc2 is HBM-bound on the 128 MB W2 read, so fewer/
// deeper blocks cost nothing, and PART shrinks 8MB->2MB (fin reads 4x less).
__global__ __launch_bounds__(256) void fc2_mfma(const float* __restrict__ W,
                                                const ushort* __restrict__ vlb,
                                                float* __restrict__ part){
  __shared__ __align__(16) float Bs[2][128 * 32];   // 2 x 16 KB, XOR-swizzled
  const int tid = threadIdx.x, lane = tid & 63, wid = tid >> 6;
  const int c0 = blockIdx.x * 128;
  const int kc = blockIdx.y;                      // 32 chunks of 1024 k
  const size_t kbase = (size_t)kc * 1024;

  const int srow = tid >> 3;                     // 0..31
  const int seg  = tid & 7;                      // 16B slot
  f32x4 acc0 = (f32x4){0.f,0.f,0.f,0.f};
  f32x4 acc1 = (f32x4){0.f,0.f,0.f,0.f};

  const int arow = lane & 15;
  const int khalf = lane >> 4;
  const int cRow0 = wid * 32 + (lane & 15);
  const int cRow1 = cRow0 + 16;

  #pragma unroll
  for(int pass = 0; pass < 4; ++pass){
    int row = pass * 32 + srow;
    const char* src = (const char*)W + (size_t)(c0 + row) * 131072
                      + kbase * 4 + ((seg ^ (row & 7)) * 16);
    gload_lds16(src, (char*)&Bs[0][0] + row * 128 + seg * 16);
  }
  __syncthreads();

  int cur = 0;
  for(int ks = 0; ks < 32; ++ks){
    if(ks + 1 < 32){
      #pragma unroll
      for(int pass = 0; pass < 4; ++pass){
        int row = pass * 32 + srow;
        const char* src = (const char*)W + (size_t)(c0 + row) * 131072
                          + (kbase + (ks + 1) * 32) * 4 + ((seg ^ (row & 7)) * 16);
        gload_lds16(src, (char*)&Bs[cur ^ 1][0] + row * 128 + seg * 16);
      }
    }
    bf16x8 af = *(const bf16x8*)((const char*)vlb + (size_t)arow * 65536
                                 + (kbase + ks * 32 + khalf * 8) * 2);
    int t0 = khalf * 2;
    const char* bsc = (const char*)&Bs[cur][0];
    float4 b00 = *(const float4*)(bsc + cRow0 * 128 + ((t0     ^ (cRow0 & 7)) * 16));
    float4 b01 = *(const float4*)(bsc + cRow0 * 128 + (((t0+1) ^ (cRow0 & 7)) * 16));
    float4 b10 = *(const float4*)(bsc + cRow1 * 128 + ((t0     ^ (cRow1 & 7)) * 16));
    float4 b11 = *(const float4*)(bsc + cRow1 * 128 + (((t0+1) ^ (cRow1 & 7)) * 16));
    bf16x8 bf0 = cvt8(b00, b01);
    bf16x8 bf1 = cvt8(b10, b11);

    acc0 = __builtin_amdgcn_mfma_f32_16x16x32_bf16(af, bf0, acc0, 0, 0, 0);
    acc1 = __builtin_amdgcn_mfma_f32_16x16x32_bf16(af, bf1, acc1, 0, 0, 0);
    __syncthreads();
    cur ^= 1;
  }

  #pragma unroll
  for(int i = 0; i < 4; ++i){
    int b = (lane >> 4) * 4 + i;
    int d0 = c0 + wid * 32 + (lane & 15);
    part[((size_t)kc * 16 + b) * 1024 + d0]      = acc0[i];
    part[((size_t)kc * 16 + b) * 1024 + d0 + 16] = acc1[i];
  }
}

// ------------- final: gscale folded in; out = relu(gs[b]*sum(part) + b2) -------
__global__ __launch_bounds__(256) void fin(const float* __restrict__ part, const float* __restrict__ ssq,
                                           const float* __restrict__ b2, float* __restrict__ out){
  int idx = blockIdx.x * 256 + threadIdx.x;   // 0..16383
  int b = idx >> 10, d = idx & 1023;
  float g = 0;
  #pragma unroll
  for(int kg = 0; kg < 16; kg++) g += ssq[b * 16 + kg];
  float gsv = 1.0f / fmaxf(sqrtf(g), 1e-12f);
  float s = 0;
  #pragma unroll
  for(int t = 0; t < 32; t++) s += part[((size_t)t * 16 + b) * 1024 + d];
  out[idx] = fmaxf(gsv * s + b2[d], 0.0f);
}

extern "C" void kernel_launch(void* const* d_in, const int* in_sizes, int n_in,
                              void* d_out, int out_size, void* d_ws, size_t ws_size,
                              hipStream_t stream){
  const float* X    = (const float*)d_in[0];
  const float* W1   = (const float*)d_in[1];
  const float* B1   = (const float*)d_in[2];
  const float* CW   = (const float*)d_in[3];
  const float* CB   = (const float*)d_in[4];
  const float* CENT = (const float*)d_in[5];
  const float* W2   = (const float*)d_in[6];
  const float* B2   = (const float*)d_in[7];
  float* out = (float*)d_out;
  char* ws = (char*)d_ws;

  float*  H    = (float*) (ws + 0);            // 33,554,432 (dead after norm)
  ushort* W1b  = (ushort*)(ws + 33554432);     //  1,048,576
  ushort* CWb  = (ushort*)(ws + 34603008);     //    131,072
  float*  CBp  = (float*) (ws + 34734080);     //        512
  ushort* XN   = (ushort*)(ws + 34734592);     // 16,777,216
  float*  LG   = (float*) (ws + 51511808);     //  8,388,608
  float*  AT   = (float*) (ws + 59900416);     //  4,194,304
  ushort* VLb  = (ushort*)(ws + 64094720);     //  1,048,576 (bf16 vlad)
  float*  SSQ  = (float*) (ws + 65143296);     //      1,024
  float*  PART = (float*) (ws + 0);            //  2,097,152 (aliases dead H)

  // prep: W1 cvt + conv_w pad/cvt + conv_b pad (one launch)
  prep<<<769, 256, 0, stream>>>(W1, CW, CB, W1b, CWb, CBp);
  // fc1 + bias + relu -> H f32, X converted in-kernel; 128x128 tiles
  gemm_fc1<<<dim3(128, 4), 256, 0, stream>>>(X, W1b, B1, H);
  // row L2 normalize -> XN bf16
  norm_rows<<<16384, 256, 0, stream>>>(H, XN);
  // logits = XN @ conv_w^T + conv_b  (N padded to 128), swizzled tiles
  gemm_bt<<<dim3(128, 1), 256, 0, stream>>>(XN, CWb, CBp, LG, 512, 128, 0);
  // softmax over k + transpose -> AT[b][k][n]
  softmax_t<<<256, 256, 0, stream>>>(LG, AT);
  // VLAD + intra-norm -> VLb bf16 + slice sumsq
  vlad_k<<<dim3(16, 16), 512, 0, stream>>>(AT, XN, CENT, VLb, SSQ);
  // fc2: MFMA, dbuf staging, K-split 32 -> 256 blocks (1/CU, deep K)
  fc2_mfma<<<dim3(8, 32), 256, 0, stream>>>(W2, VLb, PART);
  // final: gscale folded in
  fin<<<64, 256, 0, stream>>>(PART, SSQ, B2, out);
}

// Round 3
// 180.988 us; speedup vs baseline: 1.0201x; 1.0201x over previous
//
#include <hip/hip_runtime.h>
#include <hip/hip_bf16.h>

typedef __bf16  bf16x8 __attribute__((ext_vector_type(8)));
typedef float   f32x4  __attribute__((ext_vector_type(4)));

#define DEV __device__ __forceinline__

DEV ushort f2b(float f){
  union { float f; unsigned u; } c; c.f = f;
  unsigned u = c.u;
  unsigned r = (u + 0x7FFFu + ((u >> 16) & 1u)) >> 16;
  return (ushort)r;
}
DEV float b2f(ushort h){
  union { unsigned u; float f; } c; c.u = ((unsigned)h) << 16;
  return c.f;
}
DEV float wredsum(float v){
  #pragma unroll
  for(int o = 32; o > 0; o >>= 1) v += __shfl_xor(v, o, 64);
  return v;
}
DEV float wredmax(float v){
  #pragma unroll
  for(int o = 32; o > 0; o >>= 1) v = fmaxf(v, __shfl_xor(v, o, 64));
  return v;
}
DEV void gload_lds16(const void* g, void* l){
  __builtin_amdgcn_global_load_lds(
      (const __attribute__((address_space(1))) void*)g,
      (__attribute__((address_space(3))) void*)l,
      16, 0, 0);
}
DEV bf16x8 cvt8(float4 a0, float4 a1){
  bf16x8 t;
  t[0]=(__bf16)a0.x; t[1]=(__bf16)a0.y; t[2]=(__bf16)a0.z; t[3]=(__bf16)a0.w;
  t[4]=(__bf16)a1.x; t[5]=(__bf16)a1.y; t[6]=(__bf16)a1.z; t[7]=(__bf16)a1.w;
  return t;
}

// ---------------- prep: W1 f32->bf16, conv_w pad+cvt, conv_b pad --------------
__global__ void prep(const float* __restrict__ W1, const float* __restrict__ CW,
                     const float* __restrict__ CB,
                     ushort* __restrict__ W1b, ushort* __restrict__ CWb,
                     float* __restrict__ CBp){
  int bid = blockIdx.x, tid = threadIdx.x;
  if(bid < 512){
    int i = bid * 256 + tid;          // float4 index, 131072 total
    float4 f = ((const float4*)W1)[i];
    ushort4 o; o.x = f2b(f.x); o.y = f2b(f.y); o.z = f2b(f.z); o.w = f2b(f.w);
    ((ushort4*)W1b)[i] = o;
  } else if(bid < 768){
    int i = (bid - 512) * 256 + tid;  // 0..65535
    int r = i >> 9;
    CWb[i] = (r < 64) ? f2b(CW[i]) : (ushort)0;
  } else {
    if(tid < 128) CBp[tid] = (tid < 64) ? CB[tid] : 0.0f;
  }
}

// ---------------- fc1 GEMM, 128x128 tile, fused X f32->bf16 --------------------
// 4x4 fragment wave-tiles (16 MFMA / k-step / wave). Proven swizzles:
// A (f32) seg^(row&7) on 128-B rows; B (bf16) slot^((row>>1)&3) on 64-B rows,
// both pre-swizzled at the global source, read swizzled (G21).
__global__ __launch_bounds__(256) void gemm_fc1(
    const float* __restrict__ A, const ushort* __restrict__ B,
    const float* __restrict__ bias, float* __restrict__ C)
{
  const int K = 1024, N = 512;
  __shared__ __align__(16) float  Af[2][128 * 32];   // 2 x 16 KB, seg-swizzled
  __shared__ __align__(16) ushort Bs[2][128 * 32];   // 2 x 8 KB, slot-swizzled
  const int tid = threadIdx.x, lane = tid & 63, wid = tid >> 6;
  const int bm0 = blockIdx.x * 128, bn0 = blockIdx.y * 128;
  const int wr = (wid >> 1) * 64, wc = (wid & 1) * 64;

  // A staging: 128 rows x 128 B per k-step; thread -> (row = tid>>3 (+32p), seg = tid&7)
  const int srow = tid >> 3;
  const int sseg = tid & 7;
  const int sswz = sseg ^ (srow & 7);                // (srow+32p)&7 == srow&7
  const char* asrc = (const char*)A + (size_t)(bm0 + srow) * 4096 + sswz * 16;

  // B staging: row = tid>>2 (+64p), slot = tid&3; source slot pre-swizzled
  const int bslot = (tid & 3) ^ ((tid >> 3) & 3);    // ((row+64p)>>1)&3 invariant
  const ushort* bg = B + (size_t)(bn0 + (tid >> 2)) * K + bslot * 8;

  f32x4 acc[4][4];
  #pragma unroll
  for(int i = 0; i < 4; i++)
    #pragma unroll
    for(int j = 0; j < 4; j++) acc[i][j] = (f32x4){0.f, 0.f, 0.f, 0.f};

  const int arow = lane & 15;
  const int khalf = lane >> 4;

#define STAGE_FC1(buf, kb) do { \
    const char* s_ = asrc + (kb); \
    char* d_ = (char*)&Af[buf][0] + srow * 128 + sseg * 16; \
    gload_lds16(s_,             d_); \
    gload_lds16(s_ + 32 * 4096, d_ + 32 * 128); \
    gload_lds16(s_ + 64 * 4096, d_ + 64 * 128); \
    gload_lds16(s_ + 96 * 4096, d_ + 96 * 128); \
    const ushort* bs_ = bg + ((kb) >> 2); \
    gload_lds16(bs_,          &Bs[buf][tid * 8]); \
    gload_lds16(bs_ + 64 * K, &Bs[buf][2048 + tid * 8]); \
  } while(0)

  STAGE_FC1(0, 0);
  __syncthreads();

  int cur = 0;
  for(int ks = 0; ks < 32; ++ks){
    if(ks + 1 < 32) STAGE_FC1(cur ^ 1, (ks + 1) * 128);
    bf16x8 af[4], bfr[4];
    #pragma unroll
    for(int mi = 0; mi < 4; mi++){
      int r = wr + mi * 16 + arow;
      const char* base = (const char*)&Af[cur][0] + r * 128;
      float4 a0 = *(const float4*)(base + (((khalf * 2)     ^ (r & 7)) * 16));
      float4 a1 = *(const float4*)(base + (((khalf * 2 + 1) ^ (r & 7)) * 16));
      af[mi] = cvt8(a0, a1);
    }
    #pragma unroll
    for(int ni = 0; ni < 4; ni++){
      int r = wc + ni * 16 + arow;
      bfr[ni] = *(const bf16x8*)&Bs[cur][r * 32 + ((khalf ^ ((r >> 1) & 3)) * 8)];
    }
    #pragma unroll
    for(int mi = 0; mi < 4; mi++)
      #pragma unroll
      for(int ni = 0; ni < 4; ni++)
        acc[mi][ni] = __builtin_amdgcn_mfma_f32_16x16x32_bf16(af[mi], bfr[ni], acc[mi][ni], 0, 0, 0);
    __syncthreads();
    cur ^= 1;
  }
#undef STAGE_FC1

  const int crow0 = bm0 + wr + (lane >> 4) * 4;
  const int ccol0 = bn0 + wc + (lane & 15);
  #pragma unroll
  for(int mi = 0; mi < 4; mi++)
    #pragma unroll
    for(int ni = 0; ni < 4; ni++){
      int col = ccol0 + ni * 16;
      float bv = bias[col];
      #pragma unroll
      for(int i = 0; i < 4; i++){
        int row = crow0 + mi * 16 + i;
        C[(size_t)row * N + col] = fmaxf(acc[mi][ni][i] + bv, 0.f);
      }
    }
}

// ---------------- bf16 MFMA GEMM (logits), slot-swizzled tiles -----------------
__global__ __launch_bounds__(256) void gemm_bt(
    const ushort* __restrict__ A, const ushort* __restrict__ B,
    const float* __restrict__ bias, float* __restrict__ C,
    int K, int N, int relu)
{
  __shared__ __align__(16) ushort As[2][128*32];
  __shared__ __align__(16) ushort Bs[2][128*32];
  const int tid  = threadIdx.x;
  const int lane = tid & 63, wid = tid >> 6;
  const int bm0 = blockIdx.x * 128, bn0 = blockIdx.y * 128;
  const int wr = (wid >> 1) * 64, wc = (wid & 1) * 64;

  const int slot = (tid & 3) ^ ((tid >> 3) & 3);   // pre-swizzled source slot
  const ushort* ag = A + (size_t)(bm0 + (tid >> 2)) * K + slot * 8;
  const ushort* bg = B + (size_t)(bn0 + (tid >> 2)) * K + slot * 8;

  f32x4 acc[4][4];
  #pragma unroll
  for(int i = 0; i < 4; i++)
    #pragma unroll
    for(int j = 0; j < 4; j++) acc[i][j] = (f32x4){0.f, 0.f, 0.f, 0.f};

  const int arow = lane & 15;
  const int khalf = lane >> 4;
  const int nk = K >> 5;

  gload_lds16(ag,          &As[0][tid * 8]);
  gload_lds16(ag + 64 * K, &As[0][2048 + tid * 8]);
  gload_lds16(bg,          &Bs[0][tid * 8]);
  gload_lds16(bg + 64 * K, &Bs[0][2048 + tid * 8]);
  __syncthreads();

  int cur = 0;
  for(int ks = 0; ks < nk; ++ks){
    if(ks + 1 < nk){
      const ushort* agn = ag + (ks + 1) * 32;
      const ushort* bgn = bg + (ks + 1) * 32;
      gload_lds16(agn,          &As[cur ^ 1][tid * 8]);
      gload_lds16(agn + 64 * K, &As[cur ^ 1][2048 + tid * 8]);
      gload_lds16(bgn,          &Bs[cur ^ 1][tid * 8]);
      gload_lds16(bgn + 64 * K, &Bs[cur ^ 1][2048 + tid * 8]);
    }
    bf16x8 af[4], bfr[4];
    #pragma unroll
    for(int mi = 0; mi < 4; mi++){
      int r = wr + mi * 16 + arow;
      af[mi] = *(const bf16x8*)&As[cur][r * 32 + ((khalf ^ ((r >> 1) & 3)) * 8)];
    }
    #pragma unroll
    for(int ni = 0; ni < 4; ni++){
      int r = wc + ni * 16 + arow;
      bfr[ni] = *(const bf16x8*)&Bs[cur][r * 32 + ((khalf ^ ((r >> 1) & 3)) * 8)];
    }
    #pragma unroll
    for(int mi = 0; mi < 4; mi++)
      #pragma unroll
      for(int ni = 0; ni < 4; ni++)
        acc[mi][ni] = __builtin_amdgcn_mfma_f32_16x16x32_bf16(af[mi], bfr[ni], acc[mi][ni], 0, 0, 0);
    __syncthreads();
    cur ^= 1;
  }

  const int crow0 = bm0 + wr + (lane >> 4) * 4;
  const int ccol0 = bn0 + wc + (lane & 15);
  #pragma unroll
  for(int mi = 0; mi < 4; mi++)
    #pragma unroll
    for(int ni = 0; ni < 4; ni++){
      int col = ccol0 + ni * 16;
      float bv = bias[col];
      #pragma unroll
      for(int i = 0; i < 4; i++){
        int row = crow0 + mi * 16 + i;
        float v = acc[mi][ni][i] + bv;
        if(relu) v = fmaxf(v, 0.f);
        C[(size_t)row * N + col] = v;
      }
    }
}

// ---------------- per-row L2 normalize: h f32 [16384][512] -> xn bf16 ----------
__global__ __launch_bounds__(256) void norm_rows(const float* __restrict__ h, ushort* __restrict__ xn){
  __shared__ float sred[4];
  int row = blockIdx.x;
  int tid = threadIdx.x, lane = tid & 63, wid = tid >> 6;
  const float2 v = *(const float2*)&h[(size_t)row * 512 + tid * 2];
  float ss = v.x * v.x + v.y * v.y;
  ss = wredsum(ss);
  if(lane == 0) sred[wid] = ss;
  __syncthreads();
  float tot = sred[0] + sred[1] + sred[2] + sred[3];
  float sc = 1.0f / fmaxf(sqrtf(tot), 1e-12f);
  ushort2 o; o.x = f2b(v.x * sc); o.y = f2b(v.y * sc);
  *(ushort2*)&xn[(size_t)row * 512 + tid * 2] = o;
}

// ------------- softmax over 64 clusters + transpose to a_t[b][k][n] f32 --------
__global__ __launch_bounds__(256) void softmax_t(const float* __restrict__ logits, float* __restrict__ at){
  __shared__ float as_[64][65];
  int tid = threadIdx.x, lane = tid & 63, wid = tid >> 6;
  int r0 = blockIdx.x * 64;
  int b = r0 >> 10, n0 = r0 & 1023;
  for(int i = 0; i < 16; i++){
    int rl = wid * 16 + i;
    float l = logits[(size_t)(r0 + rl) * 128 + lane];
    float m = wredmax(l);
    float e = __expf(l - m);
    float s = wredsum(e);
    as_[rl][lane] = e / s;
  }
  __syncthreads();
  int nl = tid & 63;
  int kq = tid >> 6;
  for(int q = 0; q < 16; q++){
    int k = kq * 16 + q;
    at[((size_t)b * 64 + k) * 1024 + n0 + nl] = as_[nl][k];
  }
}

// ------------- VLAD aggregate + intra-normalize -> bf16, plus slice sumsq ------
__global__ __launch_bounds__(512) void vlad_k(const float* __restrict__ at, const ushort* __restrict__ xn,
                                              const float* __restrict__ cent,
                                              ushort* __restrict__ vlb, float* __restrict__ ssq){
  __shared__ float a4[4][1024];
  __shared__ float asum_s[4];
  __shared__ float red[8][4];
  __shared__ float scale_s[4];
  __shared__ float ssq_s[4];
  int tid = threadIdx.x, lane = tid & 63, wid = tid >> 6;
  int b = blockIdx.x, k0 = blockIdx.y * 4;
  #pragma unroll
  for(int u = 0; u < 2; u++){
    int idx = tid * 8 + u * 4;
    int j = idx >> 10, n = idx & 1023;
    *(float4*)&a4[j][n] = *(const float4*)&at[((size_t)b * 64 + k0 + j) * 1024 + n];
  }
  __syncthreads();
  if(wid < 4){
    float p = 0;
    for(int t = lane; t < 1024; t += 64) p += a4[wid][t];
    p = wredsum(p);
    if(lane == 0) asum_s[wid] = p;
  }
  __syncthreads();
  int h = tid;
  const ushort* xb = xn + (size_t)b * 1024 * 512 + h;
  float acc[4] = {0, 0, 0, 0};
  for(int n0 = 0; n0 < 1024; n0 += 8){
    float xv[8];
    #pragma unroll
    for(int u = 0; u < 8; u++) xv[u] = b2f(xb[(size_t)(n0 + u) * 512]);
    #pragma unroll
    for(int j = 0; j < 4; j++){
      float4 alo = *(const float4*)&a4[j][n0];
      float4 ahi = *(const float4*)&a4[j][n0 + 4];
      acc[j] += alo.x * xv[0] + alo.y * xv[1] + alo.z * xv[2] + alo.w * xv[3]
              + ahi.x * xv[4] + ahi.y * xv[5] + ahi.z * xv[6] + ahi.w * xv[7];
    }
  }
  float vl[4];
  #pragma unroll
  for(int j = 0; j < 4; j++)
    vl[j] = acc[j] - asum_s[j] * cent[(size_t)(k0 + j) * 512 + h];
  #pragma unroll
  for(int j = 0; j < 4; j++){
    float s = wredsum(vl[j] * vl[j]);
    if(lane == 0) red[wid][j] = s;
  }
  __syncthreads();
  if(tid < 4){
    float s = 0;
    #pragma unroll
    for(int w = 0; w < 8; w++) s += red[w][tid];
    float sc = 1.0f / fmaxf(sqrtf(s), 1e-12f);
    scale_s[tid] = sc;
    ssq_s[tid] = s * sc * sc;
  }
  __syncthreads();
  if(tid == 0) ssq[b * 16 + blockIdx.y] = ssq_s[0] + ssq_s[1] + ssq_s[2] + ssq_s[3];
  #pragma unroll
  for(int j = 0; j < 4; j++)
    vlb[(size_t)b * 32768 + (size_t)(k0 + j) * 512 + h] = f2b(vl[j] * scale_s[j]);
}

// ------------- fc2 via MFMA, dbuf staging, K-split 128 (4 blocks/CU) -----------
__global__ __launch_bounds__(256) void fc2_mfma(const float* __restrict__ W,
                                                const ushort* __restrict__ vlb,
                                                float* __restrict__ part){
  __shared__ __align__(16) float Bs[2][128 * 32];   // 2 x 16 KB, XOR-swizzled
  const int tid = threadIdx.x, lane = tid & 63, wid = tid >> 6;
  const int c0 = blockIdx.x * 128;
  const int kc = blockIdx.y;                      // 128 chunks of 256 k
  const size_t kbase = (size_t)kc * 256;

  const int srow = tid >> 3;                     // 0..31
  const int seg  = tid & 7;                      // 16B slot
  f32x4 acc0 = (f32x4){0.f,0.f,0.f,0.f};
  f32x4 acc1 = (f32x4){0.f,0.f,0.f,0.f};

  const int arow = lane & 15;
  const int khalf = lane >> 4;
  const int cRow0 = wid * 32 + (lane & 15);
  const int cRow1 = cRow0 + 16;

  #pragma unroll
  for(int pass = 0; pass < 4; ++pass){
    int row = pass * 32 + srow;
    const char* src = (const char*)W + (size_t)(c0 + row) * 131072
                      + kbase * 4 + ((seg ^ (row & 7)) * 16);
    gload_lds16(src, (char*)&Bs[0][0] + row * 128 + seg * 16);
  }
  __syncthreads();

  int cur = 0;
  for(int ks = 0; ks < 8; ++ks){
    if(ks + 1 < 8){
      #pragma unroll
      for(int pass = 0; pass < 4; ++pass){
        int row = pass * 32 + srow;
        const char* src = (const char*)W + (size_t)(c0 + row) * 131072
                          + (kbase + (ks + 1) * 32) * 4 + ((seg ^ (row & 7)) * 16);
        gload_lds16(src, (char*)&Bs[cur ^ 1][0] + row * 128 + seg * 16);
      }
    }
    bf16x8 af = *(const bf16x8*)((const char*)vlb + (size_t)arow * 65536
                                 + (kbase + ks * 32 + khalf * 8) * 2);
    int t0 = khalf * 2;
    const char* bsc = (const char*)&Bs[cur][0];
    float4 b00 = *(const float4*)(bsc + cRow0 * 128 + ((t0     ^ (cRow0 & 7)) * 16));
    float4 b01 = *(const float4*)(bsc + cRow0 * 128 + (((t0+1) ^ (cRow0 & 7)) * 16));
    float4 b10 = *(const float4*)(bsc + cRow1 * 128 + ((t0     ^ (cRow1 & 7)) * 16));
    float4 b11 = *(const float4*)(bsc + cRow1 * 128 + (((t0+1) ^ (cRow1 & 7)) * 16));
    bf16x8 bf0 = cvt8(b00, b01);
    bf16x8 bf1 = cvt8(b10, b11);

    acc0 = __builtin_amdgcn_mfma_f32_16x16x32_bf16(af, bf0, acc0, 0, 0, 0);
    acc1 = __builtin_amdgcn_mfma_f32_16x16x32_bf16(af, bf1, acc1, 0, 0, 0);
    __syncthreads();
    cur ^= 1;
  }

  #pragma unroll
  for(int i = 0; i < 4; ++i){
    int b = (lane >> 4) * 4 + i;
    int d0 = c0 + wid * 32 + (lane & 15);
    part[((size_t)kc * 16 + b) * 1024 + d0]      = acc0[i];
    part[((size_t)kc * 16 + b) * 1024 + d0 + 16] = acc1[i];
  }
}

// ------------- final: gscale folded in; out = relu(gs[b]*sum(part) + b2) -------
__global__ __launch_bounds__(256) void fin(const float* __restrict__ part, const float* __restrict__ ssq,
                                           const float* __restrict__ b2, float* __restrict__ out){
  int idx = blockIdx.x * 256 + threadIdx.x;   // 0..16383
  int b = idx >> 10, d = idx & 1023;
  float g = 0;
  #pragma unroll
  for(int kg = 0; kg < 16; kg++) g += ssq[b * 16 + kg];
  float gsv = 1.0f / fmaxf(sqrtf(g), 1e-12f);
  float s = 0;
  #pragma unroll
  for(int t = 0; t < 128; t++) s += part[((size_t)t * 16 + b) * 1024 + d];
  out[idx] = fmaxf(gsv * s + b2[d], 0.0f);
}

extern "C" void kernel_launch(void* const* d_in, const int* in_sizes, int n_in,
                              void* d_out, int out_size, void* d_ws, size_t ws_size,
                              hipStream_t stream){
  const float* X    = (const float*)d_in[0];
  const float* W1   = (const float*)d_in[1];
  const float* B1   = (const float*)d_in[2];
  const float* CW   = (const float*)d_in[3];
  const float* CB   = (const float*)d_in[4];
  const float* CENT = (const float*)d_in[5];
  const float* W2   = (const float*)d_in[6];
  const float* B2   = (const float*)d_in[7];
  float* out = (float*)d_out;
  char* ws = (char*)d_ws;

  float*  H    = (float*) (ws + 0);            // 33,554,432 (dead after norm)
  ushort* W1b  = (ushort*)(ws + 33554432);     //  1,048,576
  ushort* CWb  = (ushort*)(ws + 34603008);     //    131,072
  float*  CBp  = (float*) (ws + 34734080);     //        512
  ushort* XN   = (ushort*)(ws + 34734592);     // 16,777,216
  float*  LG   = (float*) (ws + 51511808);     //  8,388,608
  float*  AT   = (float*) (ws + 59900416);     //  4,194,304
  ushort* VLb  = (ushort*)(ws + 64094720);     //  1,048,576 (bf16 vlad)
  float*  SSQ  = (float*) (ws + 65143296);     //      1,024
  float*  PART = (float*) (ws + 0);            //  8,388,608 (aliases dead H)

  // prep: W1 cvt + conv_w pad/cvt + conv_b pad (one launch)
  prep<<<769, 256, 0, stream>>>(W1, CW, CB, W1b, CWb, CBp);
  // fc1 + bias + relu -> H f32, X converted in-kernel; 128x128 tiles
  gemm_fc1<<<dim3(128, 4), 256, 0, stream>>>(X, W1b, B1, H);
  // row L2 normalize -> XN bf16
  norm_rows<<<16384, 256, 0, stream>>>(H, XN);
  // logits = XN @ conv_w^T + conv_b  (N padded to 128), swizzled tiles
  gemm_bt<<<dim3(128, 1), 256, 0, stream>>>(XN, CWb, CBp, LG, 512, 128, 0);
  // softmax over k + transpose -> AT[b][k][n]
  softmax_t<<<256, 256, 0, stream>>>(LG, AT);
  // VLAD + intra-norm -> VLb bf16 + slice sumsq
  vlad_k<<<dim3(16, 16), 512, 0, stream>>>(AT, XN, CENT, VLb, SSQ);
  // fc2: MFMA, dbuf staging, K-split 128 -> 1024 blocks (4/CU)
  fc2_mfma<<<dim3(8, 128), 256, 0, stream>>>(W2, VLb, PART);
  // final: gscale folded in
  fin<<<64, 256, 0, stream>>>(PART, SSQ, B2, out);
}

// Round 4
// 174.064 us; speedup vs baseline: 1.0606x; 1.0398x over previous
//
#include <hip/hip_runtime.h>
#include <hip/hip_bf16.h>

typedef __bf16  bf16x8 __attribute__((ext_vector_type(8)));
typedef float   f32x4  __attribute__((ext_vector_type(4)));

#define DEV __device__ __forceinline__

DEV ushort f2b(float f){
  union { float f; unsigned u; } c; c.f = f;
  unsigned u = c.u;
  unsigned r = (u + 0x7FFFu + ((u >> 16) & 1u)) >> 16;
  return (ushort)r;
}
DEV float b2f(ushort h){
  union { unsigned u; float f; } c; c.u = ((unsigned)h) << 16;
  return c.f;
}
DEV float wredsum(float v){
  #pragma unroll
  for(int o = 32; o > 0; o >>= 1) v += __shfl_xor(v, o, 64);
  return v;
}
DEV float wredmax(float v){
  #pragma unroll
  for(int o = 32; o > 0; o >>= 1) v = fmaxf(v, __shfl_xor(v, o, 64));
  return v;
}
DEV void gload_lds16(const void* g, void* l){
  __builtin_amdgcn_global_load_lds(
      (const __attribute__((address_space(1))) void*)g,
      (__attribute__((address_space(3))) void*)l,
      16, 0, 0);
}
DEV bf16x8 cvt8(float4 a0, float4 a1){
  bf16x8 t;
  t[0]=(__bf16)a0.x; t[1]=(__bf16)a0.y; t[2]=(__bf16)a0.z; t[3]=(__bf16)a0.w;
  t[4]=(__bf16)a1.x; t[5]=(__bf16)a1.y; t[6]=(__bf16)a1.z; t[7]=(__bf16)a1.w;
  return t;
}

// ---------------- prep: W1 f32->bf16, conv_w pad+cvt, conv_b pad --------------
__global__ void prep(const float* __restrict__ W1, const float* __restrict__ CW,
                     const float* __restrict__ CB,
                     ushort* __restrict__ W1b, ushort* __restrict__ CWb,
                     float* __restrict__ CBp){
  int bid = blockIdx.x, tid = threadIdx.x;
  if(bid < 512){
    int i = bid * 256 + tid;          // float4 index, 131072 total
    float4 f = ((const float4*)W1)[i];
    ushort4 o; o.x = f2b(f.x); o.y = f2b(f.y); o.z = f2b(f.z); o.w = f2b(f.w);
    ((ushort4*)W1b)[i] = o;
  } else if(bid < 768){
    int i = (bid - 512) * 256 + tid;  // 0..65535
    int r = i >> 9;
    CWb[i] = (r < 64) ? f2b(CW[i]) : (ushort)0;
  } else {
    if(tid < 128) CBp[tid] = (tid < 64) ? CB[tid] : 0.0f;
  }
}

// ---------------- fc1 GEMM, 64x128 tile (R0 structure), XCD-grouped grid -------
// 1-D grid of 1024; bijective XCD swizzle (1024%8==0) maps each XCD to a
// contiguous chunk of logical ids l = bm*4+bn, so the 4 bn-tiles sharing the
// same 64 X-rows run temporally close ON THE SAME XCD -> X fetched once/L2
// instead of 4x (grid (256,4) spaced them 256 dispatches apart).
__global__ __launch_bounds__(256) void gemm_fc1(
    const float* __restrict__ A, const ushort* __restrict__ B,
    const float* __restrict__ bias, float* __restrict__ C)
{
  const int K = 1024, N = 512;
  __shared__ __align__(16) float  Af[2][64 * 32];    // 2 x 8 KB, seg-swizzled
  __shared__ __align__(16) ushort Bs[2][128 * 32];   // 2 x 8 KB, slot-swizzled
  const int tid = threadIdx.x, lane = tid & 63, wid = tid >> 6;
  const int bid = blockIdx.x;
  const int l = (bid & 7) * 128 + (bid >> 3);        // XCD-contiguous logical id
  const int bm0 = (l >> 2) * 64, bn0 = (l & 3) * 128;
  const int wr = (wid >> 1) * 32, wc = (wid & 1) * 64;

  const int srow = tid >> 3;            // 0..31 within pass (A staging)
  const int sseg = tid & 7;
  const int sswz = sseg ^ (srow & 7);
  const char* asrc = (const char*)A + (size_t)(bm0 + srow) * 4096 + sswz * 16;

  // B staging: row = tid>>2, slot = tid&3; source slot pre-swizzled
  const int bslot = (tid & 3) ^ ((tid >> 3) & 3);
  const ushort* bg = B + (size_t)(bn0 + (tid >> 2)) * K + bslot * 8;

  f32x4 acc[2][4];
  #pragma unroll
  for(int i = 0; i < 2; i++)
    #pragma unroll
    for(int j = 0; j < 4; j++) acc[i][j] = (f32x4){0.f, 0.f, 0.f, 0.f};

  const int arow = lane & 15;
  const int khalf = lane >> 4;

#define STAGE_FC1(buf, kb) do { \
    const char* s_ = asrc + (kb); \
    char* d_ = (char*)&Af[buf][0] + srow * 128 + sseg * 16; \
    gload_lds16(s_,             d_); \
    gload_lds16(s_ + 32 * 4096, d_ + 32 * 128); \
    gload_lds16(bg + ((kb) >> 2),          &Bs[buf][tid * 8]); \
    gload_lds16(bg + ((kb) >> 2) + 64 * K, &Bs[buf][2048 + tid * 8]); \
  } while(0)

  STAGE_FC1(0, 0);
  __syncthreads();

  int cur = 0;
  for(int ks = 0; ks < 32; ++ks){
    if(ks + 1 < 32) STAGE_FC1(cur ^ 1, (ks + 1) * 128);
    bf16x8 af[2], bfr[4];
    #pragma unroll
    for(int mi = 0; mi < 2; mi++){
      int r = wr + mi * 16 + arow;
      const char* base = (const char*)&Af[cur][0] + r * 128;
      float4 a0 = *(const float4*)(base + (((khalf * 2)     ^ (r & 7)) * 16));
      float4 a1 = *(const float4*)(base + (((khalf * 2 + 1) ^ (r & 7)) * 16));
      af[mi] = cvt8(a0, a1);
    }
    #pragma unroll
    for(int ni = 0; ni < 4; ni++){
      int r = wc + ni * 16 + arow;
      bfr[ni] = *(const bf16x8*)&Bs[cur][r * 32 + ((khalf ^ ((r >> 1) & 3)) * 8)];
    }
    #pragma unroll
    for(int mi = 0; mi < 2; mi++)
      #pragma unroll
      for(int ni = 0; ni < 4; ni++)
        acc[mi][ni] = __builtin_amdgcn_mfma_f32_16x16x32_bf16(af[mi], bfr[ni], acc[mi][ni], 0, 0, 0);
    __syncthreads();
    cur ^= 1;
  }
#undef STAGE_FC1

  const int crow0 = bm0 + wr + (lane >> 4) * 4;
  const int ccol0 = bn0 + wc + (lane & 15);
  #pragma unroll
  for(int mi = 0; mi < 2; mi++)
    #pragma unroll
    for(int ni = 0; ni < 4; ni++){
      int col = ccol0 + ni * 16;
      float bv = bias[col];
      #pragma unroll
      for(int i = 0; i < 4; i++){
        int row = crow0 + mi * 16 + i;
        C[(size_t)row * N + col] = fmaxf(acc[mi][ni][i] + bv, 0.f);
      }
    }
}

// ---------------- bf16 MFMA GEMM (logits), slot-swizzled tiles -----------------
__global__ __launch_bounds__(256) void gemm_bt(
    const ushort* __restrict__ A, const ushort* __restrict__ B,
    const float* __restrict__ bias, float* __restrict__ C,
    int K, int N, int relu)
{
  __shared__ __align__(16) ushort As[2][128*32];
  __shared__ __align__(16) ushort Bs[2][128*32];
  const int tid  = threadIdx.x;
  const int lane = tid & 63, wid = tid >> 6;
  const int bm0 = blockIdx.x * 128, bn0 = blockIdx.y * 128;
  const int wr = (wid >> 1) * 64, wc = (wid & 1) * 64;

  const int slot = (tid & 3) ^ ((tid >> 3) & 3);   // pre-swizzled source slot
  const ushort* ag = A + (size_t)(bm0 + (tid >> 2)) * K + slot * 8;
  const ushort* bg = B + (size_t)(bn0 + (tid >> 2)) * K + slot * 8;

  f32x4 acc[4][4];
  #pragma unroll
  for(int i = 0; i < 4; i++)
    #pragma unroll
    for(int j = 0; j < 4; j++) acc[i][j] = (f32x4){0.f, 0.f, 0.f, 0.f};

  const int arow = lane & 15;
  const int khalf = lane >> 4;
  const int nk = K >> 5;

  gload_lds16(ag,          &As[0][tid * 8]);
  gload_lds16(ag + 64 * K, &As[0][2048 + tid * 8]);
  gload_lds16(bg,          &Bs[0][tid * 8]);
  gload_lds16(bg + 64 * K, &Bs[0][2048 + tid * 8]);
  __syncthreads();

  int cur = 0;
  for(int ks = 0; ks < nk; ++ks){
    if(ks + 1 < nk){
      const ushort* agn = ag + (ks + 1) * 32;
      const ushort* bgn = bg + (ks + 1) * 32;
      gload_lds16(agn,          &As[cur ^ 1][tid * 8]);
      gload_lds16(agn + 64 * K, &As[cur ^ 1][2048 + tid * 8]);
      gload_lds16(bgn,          &Bs[cur ^ 1][tid * 8]);
      gload_lds16(bgn + 64 * K, &Bs[cur ^ 1][2048 + tid * 8]);
    }
    bf16x8 af[4], bfr[4];
    #pragma unroll
    for(int mi = 0; mi < 4; mi++){
      int r = wr + mi * 16 + arow;
      af[mi] = *(const bf16x8*)&As[cur][r * 32 + ((khalf ^ ((r >> 1) & 3)) * 8)];
    }
    #pragma unroll
    for(int ni = 0; ni < 4; ni++){
      int r = wc + ni * 16 + arow;
      bfr[ni] = *(const bf16x8*)&Bs[cur][r * 32 + ((khalf ^ ((r >> 1) & 3)) * 8)];
    }
    #pragma unroll
    for(int mi = 0; mi < 4; mi++)
      #pragma unroll
      for(int ni = 0; ni < 4; ni++)
        acc[mi][ni] = __builtin_amdgcn_mfma_f32_16x16x32_bf16(af[mi], bfr[ni], acc[mi][ni], 0, 0, 0);
    __syncthreads();
    cur ^= 1;
  }

  const int crow0 = bm0 + wr + (lane >> 4) * 4;
  const int ccol0 = bn0 + wc + (lane & 15);
  #pragma unroll
  for(int mi = 0; mi < 4; mi++)
    #pragma unroll
    for(int ni = 0; ni < 4; ni++){
      int col = ccol0 + ni * 16;
      float bv = bias[col];
      #pragma unroll
      for(int i = 0; i < 4; i++){
        int row = crow0 + mi * 16 + i;
        float v = acc[mi][ni][i] + bv;
        if(relu) v = fmaxf(v, 0.f);
        C[(size_t)row * N + col] = v;
      }
    }
}

// ---------------- per-row L2 normalize: h f32 [16384][512] -> xn bf16 ----------
__global__ __launch_bounds__(256) void norm_rows(const float* __restrict__ h, ushort* __restrict__ xn){
  __shared__ float sred[4];
  int row = blockIdx.x;
  int tid = threadIdx.x, lane = tid & 63, wid = tid >> 6;
  const float2 v = *(const float2*)&h[(size_t)row * 512 + tid * 2];
  float ss = v.x * v.x + v.y * v.y;
  ss = wredsum(ss);
  if(lane == 0) sred[wid] = ss;
  __syncthreads();
  float tot = sred[0] + sred[1] + sred[2] + sred[3];
  float sc = 1.0f / fmaxf(sqrtf(tot), 1e-12f);
  ushort2 o; o.x = f2b(v.x * sc); o.y = f2b(v.y * sc);
  *(ushort2*)&xn[(size_t)row * 512 + tid * 2] = o;
}

// ------------- softmax over 64 clusters + transpose to a_t[b][k][n] f32 --------
__global__ __launch_bounds__(256) void softmax_t(const float* __restrict__ logits, float* __restrict__ at){
  __shared__ float as_[64][65];
  int tid = threadIdx.x, lane = tid & 63, wid = tid >> 6;
  int r0 = blockIdx.x * 64;
  int b = r0 >> 10, n0 = r0 & 1023;
  for(int i = 0; i < 16; i++){
    int rl = wid * 16 + i;
    float l = logits[(size_t)(r0 + rl) * 128 + lane];
    float m = wredmax(l);
    float e = __expf(l - m);
    float s = wredsum(e);
    as_[rl][lane] = e / s;
  }
  __syncthreads();
  int nl = tid & 63;
  int kq = tid >> 6;
  for(int q = 0; q < 16; q++){
    int k = kq * 16 + q;
    at[((size_t)b * 64 + k) * 1024 + n0 + nl] = as_[nl][k];
  }
}

// ------------- VLAD aggregate + intra-normalize -> bf16, plus slice sumsq ------
__global__ __launch_bounds__(512) void vlad_k(const float* __restrict__ at, const ushort* __restrict__ xn,
                                              const float* __restrict__ cent,
                                              ushort* __restrict__ vlb, float* __restrict__ ssq){
  __shared__ float a4[4][1024];
  __shared__ float asum_s[4];
  __shared__ float red[8][4];
  __shared__ float scale_s[4];
  __shared__ float ssq_s[4];
  int tid = threadIdx.x, lane = tid & 63, wid = tid >> 6;
  int b = blockIdx.x, k0 = blockIdx.y * 4;
  #pragma unroll
  for(int u = 0; u < 2; u++){
    int idx = tid * 8 + u * 4;
    int j = idx >> 10, n = idx & 1023;
    *(float4*)&a4[j][n] = *(const float4*)&at[((size_t)b * 64 + k0 + j) * 1024 + n];
  }
  __syncthreads();
  if(wid < 4){
    float p = 0;
    for(int t = lane; t < 1024; t += 64) p += a4[wid][t];
    p = wredsum(p);
    if(lane == 0) asum_s[wid] = p;
  }
  __syncthreads();
  int h = tid;
  const ushort* xb = xn + (size_t)b * 1024 * 512 + h;
  float acc[4] = {0, 0, 0, 0};
  for(int n0 = 0; n0 < 1024; n0 += 8){
    float xv[8];
    #pragma unroll
    for(int u = 0; u < 8; u++) xv[u] = b2f(xb[(size_t)(n0 + u) * 512]);
    #pragma unroll
    for(int j = 0; j < 4; j++){
      float4 alo = *(const float4*)&a4[j][n0];
      float4 ahi = *(const float4*)&a4[j][n0 + 4];
      acc[j] += alo.x * xv[0] + alo.y * xv[1] + alo.z * xv[2] + alo.w * xv[3]
              + ahi.x * xv[4] + ahi.y * xv[5] + ahi.z * xv[6] + ahi.w * xv[7];
    }
  }
  float vl[4];
  #pragma unroll
  for(int j = 0; j < 4; j++)
    vl[j] = acc[j] - asum_s[j] * cent[(size_t)(k0 + j) * 512 + h];
  #pragma unroll
  for(int j = 0; j < 4; j++){
    float s = wredsum(vl[j] * vl[j]);
    if(lane == 0) red[wid][j] = s;
  }
  __syncthreads();
  if(tid < 4){
    float s = 0;
    #pragma unroll
    for(int w = 0; w < 8; w++) s += red[w][tid];
    float sc = 1.0f / fmaxf(sqrtf(s), 1e-12f);
    scale_s[tid] = sc;
    ssq_s[tid] = s * sc * sc;
  }
  __syncthreads();
  if(tid == 0) ssq[b * 16 + blockIdx.y] = ssq_s[0] + ssq_s[1] + ssq_s[2] + ssq_s[3];
  #pragma unroll
  for(int j = 0; j < 4; j++)
    vlb[(size_t)b * 32768 + (size_t)(k0 + j) * 512 + h] = f2b(vl[j] * scale_s[j]);
}

// ------------- fc2 via MFMA, dbuf staging, K-split 128 (4 blocks/CU) -----------
__global__ __launch_bounds__(256) void fc2_mfma(const float* __restrict__ W,
                                                const ushort* __restrict__ vlb,
                                                float* __restrict__ part){
  __shared__ __align__(16) float Bs[2][128 * 32];   // 2 x 16 KB, XOR-swizzled
  const int tid = threadIdx.x, lane = tid & 63, wid = tid >> 6;
  const int c0 = blockIdx.x * 128;
  const int kc = blockIdx.y;                      // 128 chunks of 256 k
  const size_t kbase = (size_t)kc * 256;

  const int srow = tid >> 3;                     // 0..31
  const int seg  = tid & 7;                      // 16B slot
  f32x4 acc0 = (f32x4){0.f,0.f,0.f,0.f};
  f32x4 acc1 = (f32x4){0.f,0.f,0.f,0.f};

  const int arow = lane & 15;
  const int khalf = lane >> 4;
  const int cRow0 = wid * 32 + (lane & 15);
  const int cRow1 = cRow0 + 16;

  #pragma unroll
  for(int pass = 0; pass < 4; ++pass){
    int row = pass * 32 + srow;
    const char* src = (const char*)W + (size_t)(c0 + row) * 131072
                      + kbase * 4 + ((seg ^ (row & 7)) * 16);
    gload_lds16(src, (char*)&Bs[0][0] + row * 128 + seg * 16);
  }
  __syncthreads();

  int cur = 0;
  for(int ks = 0; ks < 8; ++ks){
    if(ks + 1 < 8){
      #pragma unroll
      for(int pass = 0; pass < 4; ++pass){
        int row = pass * 32 + srow;
        const char* src = (const char*)W + (size_t)(c0 + row) * 131072
                          + (kbase + (ks + 1) * 32) * 4 + ((seg ^ (row & 7)) * 16);
        gload_lds16(src, (char*)&Bs[cur ^ 1][0] + row * 128 + seg * 16);
      }
    }
    bf16x8 af = *(const bf16x8*)((const char*)vlb + (size_t)arow * 65536
                                 + (kbase + ks * 32 + khalf * 8) * 2);
    int t0 = khalf * 2;
    const char* bsc = (const char*)&Bs[cur][0];
    float4 b00 = *(const float4*)(bsc + cRow0 * 128 + ((t0     ^ (cRow0 & 7)) * 16));
    float4 b01 = *(const float4*)(bsc + cRow0 * 128 + (((t0+1) ^ (cRow0 & 7)) * 16));
    float4 b10 = *(const float4*)(bsc + cRow1 * 128 + ((t0     ^ (cRow1 & 7)) * 16));
    float4 b11 = *(const float4*)(bsc + cRow1 * 128 + (((t0+1) ^ (cRow1 & 7)) * 16));
    bf16x8 bf0 = cvt8(b00, b01);
    bf16x8 bf1 = cvt8(b10, b11);

    acc0 = __builtin_amdgcn_mfma_f32_16x16x32_bf16(af, bf0, acc0, 0, 0, 0);
    acc1 = __builtin_amdgcn_mfma_f32_16x16x32_bf16(af, bf1, acc1, 0, 0, 0);
    __syncthreads();
    cur ^= 1;
  }

  #pragma unroll
  for(int i = 0; i < 4; ++i){
    int b = (lane >> 4) * 4 + i;
    int d0 = c0 + wid * 32 + (lane & 15);
    part[((size_t)kc * 16 + b) * 1024 + d0]      = acc0[i];
    part[((size_t)kc * 16 + b) * 1024 + d0 + 16] = acc1[i];
  }
}

// ------------- final: 4-way k-split + LDS reduce (256 blocks, was 64) ----------
// Old fin: 64 blocks = 1 wave/CU, 128 serial strided loads/thread = latency-
// bound. Now 4 waves split the 128 partials (32 each), LDS-reduce, 4x blocks.
__global__ __launch_bounds__(256) void fin(const float* __restrict__ part, const float* __restrict__ ssq,
                                           const float* __restrict__ b2, float* __restrict__ out){
  __shared__ float red[4][64];
  int lane = threadIdx.x & 63, wq = threadIdx.x >> 6;
  int o = blockIdx.x * 64 + lane;             // 0..16383
  int b = o >> 10, d = o & 1023;
  float s = 0;
  #pragma unroll
  for(int i = 0; i < 32; i++){
    int t = wq * 32 + i;
    s += part[((size_t)t * 16 + b) * 1024 + d];
  }
  red[wq][lane] = s;
  __syncthreads();
  if(wq == 0){
    float g = 0;
    #pragma unroll
    for(int kg = 0; kg < 16; kg++) g += ssq[b * 16 + kg];
    float gsv = 1.0f / fmaxf(sqrtf(g), 1e-12f);
    float tot = red[0][lane] + red[1][lane] + red[2][lane] + red[3][lane];
    out[o] = fmaxf(gsv * tot + b2[d], 0.0f);
  }
}

extern "C" void kernel_launch(void* const* d_in, const int* in_sizes, int n_in,
                              void* d_out, int out_size, void* d_ws, size_t ws_size,
                              hipStream_t stream){
  const float* X    = (const float*)d_in[0];
  const float* W1   = (const float*)d_in[1];
  const float* B1   = (const float*)d_in[2];
  const float* CW   = (const float*)d_in[3];
  const float* CB   = (const float*)d_in[4];
  const float* CENT = (const float*)d_in[5];
  const float* W2   = (const float*)d_in[6];
  const float* B2   = (const float*)d_in[7];
  float* out = (float*)d_out;
  char* ws = (char*)d_ws;

  float*  H    = (float*) (ws + 0);            // 33,554,432 (dead after norm)
  ushort* W1b  = (ushort*)(ws + 33554432);     //  1,048,576
  ushort* CWb  = (ushort*)(ws + 34603008);     //    131,072
  float*  CBp  = (float*) (ws + 34734080);     //        512
  ushort* XN   = (ushort*)(ws + 34734592);     // 16,777,216
  float*  LG   = (float*) (ws + 51511808);     //  8,388,608
  float*  AT   = (float*) (ws + 59900416);     //  4,194,304
  ushort* VLb  = (ushort*)(ws + 64094720);     //  1,048,576 (bf16 vlad)
  float*  SSQ  = (float*) (ws + 65143296);     //      1,024
  float*  PART = (float*) (ws + 0);            //  8,388,608 (aliases dead H)

  // prep: W1 cvt + conv_w pad/cvt + conv_b pad (one launch)
  prep<<<769, 256, 0, stream>>>(W1, CW, CB, W1b, CWb, CBp);
  // fc1 + bias + relu -> H f32; 64x128 tiles, XCD-grouped 1-D grid
  gemm_fc1<<<1024, 256, 0, stream>>>(X, W1b, B1, H);
  // row L2 normalize -> XN bf16
  norm_rows<<<16384, 256, 0, stream>>>(H, XN);
  // logits = XN @ conv_w^T + conv_b  (N padded to 128), swizzled tiles
  gemm_bt<<<dim3(128, 1), 256, 0, stream>>>(XN, CWb, CBp, LG, 512, 128, 0);
  // softmax over k + transpose -> AT[b][k][n]
  softmax_t<<<256, 256, 0, stream>>>(LG, AT);
  // VLAD + intra-norm -> VLb bf16 + slice sumsq
  vlad_k<<<dim3(16, 16), 512, 0, stream>>>(AT, XN, CENT, VLb, SSQ);
  // fc2: MFMA, dbuf staging, K-split 128 -> 1024 blocks (4/CU)
  fc2_mfma<<<dim3(8, 128), 256, 0, stream>>>(W2, VLb, PART);
  // final: gscale folded in; 4-way k-split + LDS reduce
  fin<<<256, 256, 0, stream>>>(PART, SSQ, B2, out);
}

// Round 5
// 159.466 us; speedup vs baseline: 1.1577x; 1.0915x over previous
//
#include <hip/hip_runtime.h>
#include <hip/hip_bf16.h>

typedef __bf16  bf16x8 __attribute__((ext_vector_type(8)));
typedef float   f32x4  __attribute__((ext_vector_type(4)));

#define DEV __device__ __forceinline__

DEV ushort f2b(float f){
  union { float f; unsigned u; } c; c.f = f;
  unsigned u = c.u;
  unsigned r = (u + 0x7FFFu + ((u >> 16) & 1u)) >> 16;
  return (ushort)r;
}
DEV float b2f(ushort h){
  union { unsigned u; float f; } c; c.u = ((unsigned)h) << 16;
  return c.f;
}
DEV float wredsum(float v){
  #pragma unroll
  for(int o = 32; o > 0; o >>= 1) v += __shfl_xor(v, o, 64);
  return v;
}
DEV float wredmax(float v){
  #pragma unroll
  for(int o = 32; o > 0; o >>= 1) v = fmaxf(v, __shfl_xor(v, o, 64));
  return v;
}
DEV void gload_lds16(const void* g, void* l){
  __builtin_amdgcn_global_load_lds(
      (const __attribute__((address_space(1))) void*)g,
      (__attribute__((address_space(3))) void*)l,
      16, 0, 0);
}
DEV bf16x8 cvt8(float4 a0, float4 a1){
  bf16x8 t;
  t[0]=(__bf16)a0.x; t[1]=(__bf16)a0.y; t[2]=(__bf16)a0.z; t[3]=(__bf16)a0.w;
  t[4]=(__bf16)a1.x; t[5]=(__bf16)a1.y; t[6]=(__bf16)a1.z; t[7]=(__bf16)a1.w;
  return t;
}

// ---------------- prep: W1 f32->bf16, conv_w pad+cvt, conv_b pad --------------
__global__ void prep(const float* __restrict__ W1, const float* __restrict__ CW,
                     const float* __restrict__ CB,
                     ushort* __restrict__ W1b, ushort* __restrict__ CWb,
                     float* __restrict__ CBp){
  int bid = blockIdx.x, tid = threadIdx.x;
  if(bid < 512){
    int i = bid * 256 + tid;          // float4 index, 131072 total
    float4 f = ((const float4*)W1)[i];
    ushort4 o; o.x = f2b(f.x); o.y = f2b(f.y); o.z = f2b(f.z); o.w = f2b(f.w);
    ((ushort4*)W1b)[i] = o;
  } else if(bid < 768){
    int i = (bid - 512) * 256 + tid;  // 0..65535
    int r = i >> 9;
    CWb[i] = (r < 64) ? f2b(CW[i]) : (ushort)0;
  } else {
    if(tid < 128) CBp[tid] = (tid < 64) ? CB[tid] : 0.0f;
  }
}

// ------- fc1n: fused fc1 GEMM (64x512 full-width tile) + bias + relu + L2norm --
// 512 threads / 8 waves (2 row-waves x 4 col-waves; wave tile 32x128).
// Full 512-col rows per block -> row norm computed in epilogue, XN bf16 written
// directly. Eliminates H f32 (32MB W + 32MB R) and the norm_rows kernel.
// A (f32) seg^(row&7) swizzle on 128-B rows; B (bf16) slot^((row>>1)&3) on
// 64-B rows; both pre-swizzled at source, read swizzled (proven pattern).
__global__ __launch_bounds__(512) void fc1n(
    const float* __restrict__ A, const ushort* __restrict__ B,
    const float* __restrict__ bias, ushort* __restrict__ XN)
{
  const int K = 1024;
  __shared__ __align__(16) float  Af[2][64 * 32];    // 2 x 8 KB
  __shared__ __align__(16) ushort Bs[2][512 * 32];   // 2 x 32 KB
  __shared__ float ssq_p[4][64];
  __shared__ float scale_s[64];
  const int tid = threadIdx.x, lane = tid & 63, wid = tid >> 6;
  const int bm0 = blockIdx.x * 64;
  const int wr = (wid >> 2) * 32;          // 0 / 32
  const int wc = (wid & 3) * 128;          // 0 / 128 / 256 / 384
  const int wcol = wid & 3;

  // A staging: 64 rows x 128 B -> 512 loads, 1/thread
  const int srow = tid >> 3;               // 0..63
  const int sseg = tid & 7;
  const char* asrc = (const char*)A + (size_t)(bm0 + srow) * 4096
                     + (sseg ^ (srow & 7)) * 16;
  // B staging: 512 rows x 64 B -> 2048 loads, 4/thread (rows tid>>2 + 128p)
  const int bslot = (tid & 3) ^ ((tid >> 3) & 3);   // ((row+128p)>>1)&3 invariant
  const ushort* bg = B + (size_t)(tid >> 2) * K + bslot * 8;

  f32x4 acc[2][8];
  #pragma unroll
  for(int i = 0; i < 2; i++)
    #pragma unroll
    for(int j = 0; j < 8; j++) acc[i][j] = (f32x4){0.f, 0.f, 0.f, 0.f};

  const int arow = lane & 15;
  const int khalf = lane >> 4;

#define STAGE_F1N(buf, kb) do { \
    gload_lds16(asrc + (kb), (char*)&Af[buf][0] + tid * 16); \
    const ushort* bs_ = bg + ((kb) >> 2); \
    gload_lds16(bs_,            &Bs[buf][tid * 8]); \
    gload_lds16(bs_ + 128 * K,  &Bs[buf][ 4096 + tid * 8]); \
    gload_lds16(bs_ + 256 * K,  &Bs[buf][ 8192 + tid * 8]); \
    gload_lds16(bs_ + 384 * K,  &Bs[buf][12288 + tid * 8]); \
  } while(0)

  STAGE_F1N(0, 0);
  __syncthreads();

  int cur = 0;
  for(int ks = 0; ks < 32; ++ks){
    if(ks + 1 < 32) STAGE_F1N(cur ^ 1, (ks + 1) * 128);
    bf16x8 af[2], bfr[8];
    #pragma unroll
    for(int mi = 0; mi < 2; mi++){
      int r = wr + mi * 16 + arow;
      const char* base = (const char*)&Af[cur][0] + r * 128;
      float4 a0 = *(const float4*)(base + (((khalf * 2)     ^ (r & 7)) * 16));
      float4 a1 = *(const float4*)(base + (((khalf * 2 + 1) ^ (r & 7)) * 16));
      af[mi] = cvt8(a0, a1);
    }
    #pragma unroll
    for(int ni = 0; ni < 8; ni++){
      int r = wc + ni * 16 + arow;
      bfr[ni] = *(const bf16x8*)&Bs[cur][r * 32 + ((khalf ^ ((r >> 1) & 3)) * 8)];
    }
    #pragma unroll
    for(int mi = 0; mi < 2; mi++)
      #pragma unroll
      for(int ni = 0; ni < 8; ni++)
        acc[mi][ni] = __builtin_amdgcn_mfma_f32_16x16x32_bf16(af[mi], bfr[ni], acc[mi][ni], 0, 0, 0);
    __syncthreads();
    cur ^= 1;
  }
#undef STAGE_F1N

  // epilogue: bias + relu, per-row sum-of-squares, scale, emit bf16
  float bv[8];
  #pragma unroll
  for(int ni = 0; ni < 8; ni++) bv[ni] = bias[wc + ni * 16 + (lane & 15)];
  float p[2][4];
  #pragma unroll
  for(int mi = 0; mi < 2; mi++)
    #pragma unroll
    for(int i = 0; i < 4; i++){
      float s = 0.f;
      #pragma unroll
      for(int ni = 0; ni < 8; ni++){
        float v = fmaxf(acc[mi][ni][i] + bv[ni], 0.f);
        acc[mi][ni][i] = v;
        s += v * v;
      }
      p[mi][i] = s;
    }
  // reduce across the 16 col-lanes of each row
  #pragma unroll
  for(int o = 1; o < 16; o <<= 1)
    #pragma unroll
    for(int mi = 0; mi < 2; mi++)
      #pragma unroll
      for(int i = 0; i < 4; i++)
        p[mi][i] += __shfl_xor(p[mi][i], o, 64);
  if((lane & 15) == 0){
    int g = lane >> 4;
    #pragma unroll
    for(int mi = 0; mi < 2; mi++)
      #pragma unroll
      for(int i = 0; i < 4; i++)
        ssq_p[wcol][wr + mi * 16 + g * 4 + i] = p[mi][i];
  }
  __syncthreads();
  if(tid < 64){
    float s = ssq_p[0][tid] + ssq_p[1][tid] + ssq_p[2][tid] + ssq_p[3][tid];
    scale_s[tid] = 1.0f / fmaxf(sqrtf(s), 1e-12f);
  }
  __syncthreads();
  #pragma unroll
  for(int mi = 0; mi < 2; mi++)
    #pragma unroll
    for(int i = 0; i < 4; i++){
      int rt = wr + mi * 16 + (lane >> 4) * 4 + i;
      float sc = scale_s[rt];
      #pragma unroll
      for(int ni = 0; ni < 8; ni++)
        XN[(size_t)(bm0 + rt) * 512 + wc + ni * 16 + (lane & 15)] = f2b(acc[mi][ni][i] * sc);
    }
}

// -------- logits GEMM: 64x128 tile, 256 blocks (full GPU; was 128) -------------
__global__ __launch_bounds__(256) void gemm_lg(
    const ushort* __restrict__ A, const ushort* __restrict__ B,
    const float* __restrict__ bias, float* __restrict__ C)
{
  const int K = 512;
  __shared__ __align__(16) ushort As[2][64 * 32];    // 2 x 4 KB
  __shared__ __align__(16) ushort Bs[2][128 * 32];   // 2 x 8 KB
  const int tid  = threadIdx.x;
  const int lane = tid & 63, wid = tid >> 6;
  const int bm0 = blockIdx.x * 64;
  const int wr = (wid >> 1) * 32, wc = (wid & 1) * 64;

  const int slot = (tid & 3) ^ ((tid >> 3) & 3);
  const ushort* ag = A + (size_t)(bm0 + (tid >> 2)) * K + slot * 8;
  const ushort* bg = B + (size_t)(tid >> 2) * K + slot * 8;

  f32x4 acc[2][4];
  #pragma unroll
  for(int i = 0; i < 2; i++)
    #pragma unroll
    for(int j = 0; j < 4; j++) acc[i][j] = (f32x4){0.f, 0.f, 0.f, 0.f};

  const int arow = lane & 15;
  const int khalf = lane >> 4;

  gload_lds16(ag,          &As[0][tid * 8]);
  gload_lds16(bg,          &Bs[0][tid * 8]);
  gload_lds16(bg + 64 * K, &Bs[0][2048 + tid * 8]);
  __syncthreads();

  int cur = 0;
  for(int ks = 0; ks < 16; ++ks){
    if(ks + 1 < 16){
      const ushort* agn = ag + (ks + 1) * 32;
      const ushort* bgn = bg + (ks + 1) * 32;
      gload_lds16(agn,          &As[cur ^ 1][tid * 8]);
      gload_lds16(bgn,          &Bs[cur ^ 1][tid * 8]);
      gload_lds16(bgn + 64 * K, &Bs[cur ^ 1][2048 + tid * 8]);
    }
    bf16x8 af[2], bfr[4];
    #pragma unroll
    for(int mi = 0; mi < 2; mi++){
      int r = wr + mi * 16 + arow;
      af[mi] = *(const bf16x8*)&As[cur][r * 32 + ((khalf ^ ((r >> 1) & 3)) * 8)];
    }
    #pragma unroll
    for(int ni = 0; ni < 4; ni++){
      int r = wc + ni * 16 + arow;
      bfr[ni] = *(const bf16x8*)&Bs[cur][r * 32 + ((khalf ^ ((r >> 1) & 3)) * 8)];
    }
    #pragma unroll
    for(int mi = 0; mi < 2; mi++)
      #pragma unroll
      for(int ni = 0; ni < 4; ni++)
        acc[mi][ni] = __builtin_amdgcn_mfma_f32_16x16x32_bf16(af[mi], bfr[ni], acc[mi][ni], 0, 0, 0);
    __syncthreads();
    cur ^= 1;
  }

  const int crow0 = bm0 + wr + (lane >> 4) * 4;
  #pragma unroll
  for(int mi = 0; mi < 2; mi++)
    #pragma unroll
    for(int ni = 0; ni < 4; ni++){
      int col = wc + ni * 16 + (lane & 15);
      if(col < 64){
        float bvv = bias[col];
        #pragma unroll
        for(int i = 0; i < 4; i++){
          int row = crow0 + mi * 16 + i;
          C[(size_t)row * 128 + col] = acc[mi][ni][i] + bvv;
        }
      }
    }
}

// ------------- softmax over 64 clusters + transpose to a_t[b][k][n] f32 --------
__global__ __launch_bounds__(256) void softmax_t(const float* __restrict__ logits, float* __restrict__ at){
  __shared__ float as_[64][65];
  int tid = threadIdx.x, lane = tid & 63, wid = tid >> 6;
  int r0 = blockIdx.x * 64;
  int b = r0 >> 10, n0 = r0 & 1023;
  for(int i = 0; i < 16; i++){
    int rl = wid * 16 + i;
    float l = logits[(size_t)(r0 + rl) * 128 + lane];
    float m = wredmax(l);
    float e = __expf(l - m);
    float s = wredsum(e);
    as_[rl][lane] = e / s;
  }
  __syncthreads();
  int nl = tid & 63;
  int kq = tid >> 6;
  for(int q = 0; q < 16; q++){
    int k = kq * 16 + q;
    at[((size_t)b * 64 + k) * 1024 + n0 + nl] = as_[nl][k];
  }
}

// ------------- VLAD aggregate + intra-normalize -> bf16, plus slice sumsq ------
__global__ __launch_bounds__(512) void vlad_k(const float* __restrict__ at, const ushort* __restrict__ xn,
                                              const float* __restrict__ cent,
                                              ushort* __restrict__ vlb, float* __restrict__ ssq){
  __shared__ float a4[4][1024];
  __shared__ float asum_s[4];
  __shared__ float red[8][4];
  __shared__ float scale_s[4];
  __shared__ float ssq_s[4];
  int tid = threadIdx.x, lane = tid & 63, wid = tid >> 6;
  int b = blockIdx.x, k0 = blockIdx.y * 4;
  #pragma unroll
  for(int u = 0; u < 2; u++){
    int idx = tid * 8 + u * 4;
    int j = idx >> 10, n = idx & 1023;
    *(float4*)&a4[j][n] = *(const float4*)&at[((size_t)b * 64 + k0 + j) * 1024 + n];
  }
  __syncthreads();
  if(wid < 4){
    float p = 0;
    for(int t = lane; t < 1024; t += 64) p += a4[wid][t];
    p = wredsum(p);
    if(lane == 0) asum_s[wid] = p;
  }
  __syncthreads();
  int h = tid;
  const ushort* xb = xn + (size_t)b * 1024 * 512 + h;
  float acc[4] = {0, 0, 0, 0};
  for(int n0 = 0; n0 < 1024; n0 += 8){
    float xv[8];
    #pragma unroll
    for(int u = 0; u < 8; u++) xv[u] = b2f(xb[(size_t)(n0 + u) * 512]);
    #pragma unroll
    for(int j = 0; j < 4; j++){
      float4 alo = *(const float4*)&a4[j][n0];
      float4 ahi = *(const float4*)&a4[j][n0 + 4];
      acc[j] += alo.x * xv[0] + alo.y * xv[1] + alo.z * xv[2] + alo.w * xv[3]
              + ahi.x * xv[4] + ahi.y * xv[5] + ahi.z * xv[6] + ahi.w * xv[7];
    }
  }
  float vl[4];
  #pragma unroll
  for(int j = 0; j < 4; j++)
    vl[j] = acc[j] - asum_s[j] * cent[(size_t)(k0 + j) * 512 + h];
  #pragma unroll
  for(int j = 0; j < 4; j++){
    float s = wredsum(vl[j] * vl[j]);
    if(lane == 0) red[wid][j] = s;
  }
  __syncthreads();
  if(tid < 4){
    float s = 0;
    #pragma unroll
    for(int w = 0; w < 8; w++) s += red[w][tid];
    float sc = 1.0f / fmaxf(sqrtf(s), 1e-12f);
    scale_s[tid] = sc;
    ssq_s[tid] = s * sc * sc;
  }
  __syncthreads();
  if(tid == 0) ssq[b * 16 + blockIdx.y] = ssq_s[0] + ssq_s[1] + ssq_s[2] + ssq_s[3];
  #pragma unroll
  for(int j = 0; j < 4; j++)
    vlb[(size_t)b * 32768 + (size_t)(k0 + j) * 512 + h] = f2b(vl[j] * scale_s[j]);
}

// ------------- fc2 via MFMA, dbuf staging, K-split 128 (4 blocks/CU) -----------
__global__ __launch_bounds__(256) void fc2_mfma(const float* __restrict__ W,
                                                const ushort* __restrict__ vlb,
                                                float* __restrict__ part){
  __shared__ __align__(16) float Bs[2][128 * 32];   // 2 x 16 KB, XOR-swizzled
  const int tid = threadIdx.x, lane = tid & 63, wid = tid >> 6;
  const int c0 = blockIdx.x * 128;
  const int kc = blockIdx.y;                      // 128 chunks of 256 k
  const size_t kbase = (size_t)kc * 256;

  const int srow = tid >> 3;                     // 0..31
  const int seg  = tid & 7;                      // 16B slot
  f32x4 acc0 = (f32x4){0.f,0.f,0.f,0.f};
  f32x4 acc1 = (f32x4){0.f,0.f,0.f,0.f};

  const int arow = lane & 15;
  const int khalf = lane >> 4;
  const int cRow0 = wid * 32 + (lane & 15);
  const int cRow1 = cRow0 + 16;

  #pragma unroll
  for(int pass = 0; pass < 4; ++pass){
    int row = pass * 32 + srow;
    const char* src = (const char*)W + (size_t)(c0 + row) * 131072
                      + kbase * 4 + ((seg ^ (row & 7)) * 16);
    gload_lds16(src, (char*)&Bs[0][0] + row * 128 + seg * 16);
  }
  __syncthreads();

  int cur = 0;
  for(int ks = 0; ks < 8; ++ks){
    if(ks + 1 < 8){
      #pragma unroll
      for(int pass = 0; pass < 4; ++pass){
        int row = pass * 32 + srow;
        const char* src = (const char*)W + (size_t)(c0 + row) * 131072
                          + (kbase + (ks + 1) * 32) * 4 + ((seg ^ (row & 7)) * 16);
        gload_lds16(src, (char*)&Bs[cur ^ 1][0] + row * 128 + seg * 16);
      }
    }
    bf16x8 af = *(const bf16x8*)((const char*)vlb + (size_t)arow * 65536
                                 + (kbase + ks * 32 + khalf * 8) * 2);
    int t0 = khalf * 2;
    const char* bsc = (const char*)&Bs[cur][0];
    float4 b00 = *(const float4*)(bsc + cRow0 * 128 + ((t0     ^ (cRow0 & 7)) * 16));
    float4 b01 = *(const float4*)(bsc + cRow0 * 128 + (((t0+1) ^ (cRow0 & 7)) * 16));
    float4 b10 = *(const float4*)(bsc + cRow1 * 128 + ((t0     ^ (cRow1 & 7)) * 16));
    float4 b11 = *(const float4*)(bsc + cRow1 * 128 + (((t0+1) ^ (cRow1 & 7)) * 16));
    bf16x8 bf0 = cvt8(b00, b01);
    bf16x8 bf1 = cvt8(b10, b11);

    acc0 = __builtin_amdgcn_mfma_f32_16x16x32_bf16(af, bf0, acc0, 0, 0, 0);
    acc1 = __builtin_amdgcn_mfma_f32_16x16x32_bf16(af, bf1, acc1, 0, 0, 0);
    __syncthreads();
    cur ^= 1;
  }

  #pragma unroll
  for(int i = 0; i < 4; ++i){
    int b = (lane >> 4) * 4 + i;
    int d0 = c0 + wid * 32 + (lane & 15);
    part[((size_t)kc * 16 + b) * 1024 + d0]      = acc0[i];
    part[((size_t)kc * 16 + b) * 1024 + d0 + 16] = acc1[i];
  }
}

// ------------- final: 4-way k-split + LDS reduce (256 blocks) ------------------
__global__ __launch_bounds__(256) void fin(const float* __restrict__ part, const float* __restrict__ ssq,
                                           const float* __restrict__ b2, float* __restrict__ out){
  __shared__ float red[4][64];
  int lane = threadIdx.x & 63, wq = threadIdx.x >> 6;
  int o = blockIdx.x * 64 + lane;             // 0..16383
  int b = o >> 10, d = o & 1023;
  float s = 0;
  #pragma unroll
  for(int i = 0; i < 32; i++){
    int t = wq * 32 + i;
    s += part[((size_t)t * 16 + b) * 1024 + d];
  }
  red[wq][lane] = s;
  __syncthreads();
  if(wq == 0){
    float g = 0;
    #pragma unroll
    for(int kg = 0; kg < 16; kg++) g += ssq[b * 16 + kg];
    float gsv = 1.0f / fmaxf(sqrtf(g), 1e-12f);
    float tot = red[0][lane] + red[1][lane] + red[2][lane] + red[3][lane];
    out[o] = fmaxf(gsv * tot + b2[d], 0.0f);
  }
}

extern "C" void kernel_launch(void* const* d_in, const int* in_sizes, int n_in,
                              void* d_out, int out_size, void* d_ws, size_t ws_size,
                              hipStream_t stream){
  const float* X    = (const float*)d_in[0];
  const float* W1   = (const float*)d_in[1];
  const float* B1   = (const float*)d_in[2];
  const float* CW   = (const float*)d_in[3];
  const float* CB   = (const float*)d_in[4];
  const float* CENT = (const float*)d_in[5];
  const float* W2   = (const float*)d_in[6];
  const float* B2   = (const float*)d_in[7];
  float* out = (float*)d_out;
  char* ws = (char*)d_ws;

  ushort* W1b  = (ushort*)(ws + 0);            //  1,048,576
  ushort* CWb  = (ushort*)(ws + 1048576);      //    131,072
  float*  CBp  = (float*) (ws + 1179648);      //        512
  ushort* XN   = (ushort*)(ws + 1180160);      // 16,777,216
  float*  LG   = (float*) (ws + 17957376);     //  8,388,608
  float*  AT   = (float*) (ws + 26345984);     //  4,194,304
  ushort* VLb  = (ushort*)(ws + 30540288);     //  1,048,576 (bf16 vlad)
  float*  SSQ  = (float*) (ws + 31588864);     //      1,024
  float*  PART = (float*) (ws + 31590400);     //  8,388,608

  // prep: W1 cvt + conv_w pad/cvt + conv_b pad (one launch)
  prep<<<769, 256, 0, stream>>>(W1, CW, CB, W1b, CWb, CBp);
  // fused fc1 + bias + relu + row-L2norm -> XN bf16 (no H, no norm_rows)
  fc1n<<<256, 512, 0, stream>>>(X, W1b, B1, XN);
  // logits = XN @ conv_w^T + conv_b ; 64-row tiles, 256 blocks
  gemm_lg<<<256, 256, 0, stream>>>(XN, CWb, CBp, LG);
  // softmax over k + transpose -> AT[b][k][n]
  softmax_t<<<256, 256, 0, stream>>>(LG, AT);
  // VLAD + intra-norm -> VLb bf16 + slice sumsq
  vlad_k<<<dim3(16, 16), 512, 0, stream>>>(AT, XN, CENT, VLb, SSQ);
  // fc2: MFMA, dbuf staging, K-split 128 -> 1024 blocks (4/CU)
  fc2_mfma<<<dim3(8, 128), 256, 0, stream>>>(W2, VLb, PART);
  // final: gscale folded in; 4-way k-split + LDS reduce
  fin<<<256, 256, 0, stream>>>(PART, SSQ, B2, out);
}

// Round 6
// 146.296 us; speedup vs baseline: 1.2620x; 1.0900x over previous
//
#include <hip/hip_runtime.h>
#include <hip/hip_bf16.h>

typedef __bf16  bf16x8 __attribute__((ext_vector_type(8)));
typedef float   f32x4  __attribute__((ext_vector_type(4)));

#define DEV __device__ __forceinline__

DEV ushort f2b(float f){
  union { float f; unsigned u; } c; c.f = f;
  unsigned u = c.u;
  unsigned r = (u + 0x7FFFu + ((u >> 16) & 1u)) >> 16;
  return (ushort)r;
}
DEV float b2f(ushort h){
  union { unsigned u; float f; } c; c.u = ((unsigned)h) << 16;
  return c.f;
}
DEV float wredsum(float v){
  #pragma unroll
  for(int o = 32; o > 0; o >>= 1) v += __shfl_xor(v, o, 64);
  return v;
}
DEV void gload_lds16(const void* g, void* l){
  __builtin_amdgcn_global_load_lds(
      (const __attribute__((address_space(1))) void*)g,
      (__attribute__((address_space(3))) void*)l,
      16, 0, 0);
}
DEV bf16x8 cvt8(float4 a0, float4 a1){
  bf16x8 t;
  t[0]=(__bf16)a0.x; t[1]=(__bf16)a0.y; t[2]=(__bf16)a0.z; t[3]=(__bf16)a0.w;
  t[4]=(__bf16)a1.x; t[5]=(__bf16)a1.y; t[6]=(__bf16)a1.z; t[7]=(__bf16)a1.w;
  return t;
}

// ---------------- prep: W1 f32->bf16, conv_w pad+cvt, conv_b pad --------------
__global__ void prep(const float* __restrict__ W1, const float* __restrict__ CW,
                     const float* __restrict__ CB,
                     ushort* __restrict__ W1b, ushort* __restrict__ CWb,
                     float* __restrict__ CBp){
  int bid = blockIdx.x, tid = threadIdx.x;
  if(bid < 512){
    int i = bid * 256 + tid;          // float4 index, 131072 total
    float4 f = ((const float4*)W1)[i];
    ushort4 o; o.x = f2b(f.x); o.y = f2b(f.y); o.z = f2b(f.z); o.w = f2b(f.w);
    ((ushort4*)W1b)[i] = o;
  } else if(bid < 768){
    int i = (bid - 512) * 256 + tid;  // 0..65535
    int r = i >> 9;
    CWb[i] = (r < 64) ? f2b(CW[i]) : (ushort)0;
  } else {
    if(tid < 128) CBp[tid] = (tid < 64) ? CB[tid] : 0.0f;
  }
}

// ------- fc1n: fused fc1 GEMM (64x512 full-width tile) + bias + relu + L2norm --
// 512 threads / 8 waves (2 row-waves x 4 col-waves; wave tile 32x128).
// Full 512-col rows per block -> row norm computed in epilogue, XN bf16 written
// directly. A (f32) seg^(row&7) swizzle on 128-B rows; B (bf16)
// slot^((row>>1)&3) on 64-B rows; pre-swizzled at source, read swizzled.
__global__ __launch_bounds__(512) void fc1n(
    const float* __restrict__ A, const ushort* __restrict__ B,
    const float* __restrict__ bias, ushort* __restrict__ XN)
{
  const int K = 1024;
  __shared__ __align__(16) float  Af[2][64 * 32];    // 2 x 8 KB
  __shared__ __align__(16) ushort Bs[2][512 * 32];   // 2 x 32 KB
  __shared__ float ssq_p[4][64];
  __shared__ float scale_s[64];
  const int tid = threadIdx.x, lane = tid & 63, wid = tid >> 6;
  const int bm0 = blockIdx.x * 64;
  const int wr = (wid >> 2) * 32;          // 0 / 32
  const int wc = (wid & 3) * 128;          // 0 / 128 / 256 / 384
  const int wcol = wid & 3;

  // A staging: 64 rows x 128 B -> 512 loads, 1/thread
  const int srow = tid >> 3;               // 0..63
  const int sseg = tid & 7;
  const char* asrc = (const char*)A + (size_t)(bm0 + srow) * 4096
                     + (sseg ^ (srow & 7)) * 16;
  // B staging: 512 rows x 64 B -> 2048 loads, 4/thread (rows tid>>2 + 128p)
  const int bslot = (tid & 3) ^ ((tid >> 3) & 3);   // ((row+128p)>>1)&3 invariant
  const ushort* bg = B + (size_t)(tid >> 2) * K + bslot * 8;

  f32x4 acc[2][8];
  #pragma unroll
  for(int i = 0; i < 2; i++)
    #pragma unroll
    for(int j = 0; j < 8; j++) acc[i][j] = (f32x4){0.f, 0.f, 0.f, 0.f};

  const int arow = lane & 15;
  const int khalf = lane >> 4;

#define STAGE_F1N(buf, kb) do { \
    gload_lds16(asrc + (kb), (char*)&Af[buf][0] + tid * 16); \
    const ushort* bs_ = bg + ((kb) >> 2); \
    gload_lds16(bs_,            &Bs[buf][tid * 8]); \
    gload_lds16(bs_ + 128 * K,  &Bs[buf][ 4096 + tid * 8]); \
    gload_lds16(bs_ + 256 * K,  &Bs[buf][ 8192 + tid * 8]); \
    gload_lds16(bs_ + 384 * K,  &Bs[buf][12288 + tid * 8]); \
  } while(0)

  STAGE_F1N(0, 0);
  __syncthreads();

  int cur = 0;
  for(int ks = 0; ks < 32; ++ks){
    if(ks + 1 < 32) STAGE_F1N(cur ^ 1, (ks + 1) * 128);
    bf16x8 af[2], bfr[8];
    #pragma unroll
    for(int mi = 0; mi < 2; mi++){
      int r = wr + mi * 16 + arow;
      const char* base = (const char*)&Af[cur][0] + r * 128;
      float4 a0 = *(const float4*)(base + (((khalf * 2)     ^ (r & 7)) * 16));
      float4 a1 = *(const float4*)(base + (((khalf * 2 + 1) ^ (r & 7)) * 16));
      af[mi] = cvt8(a0, a1);
    }
    #pragma unroll
    for(int ni = 0; ni < 8; ni++){
      int r = wc + ni * 16 + arow;
      bfr[ni] = *(const bf16x8*)&Bs[cur][r * 32 + ((khalf ^ ((r >> 1) & 3)) * 8)];
    }
    #pragma unroll
    for(int mi = 0; mi < 2; mi++)
      #pragma unroll
      for(int ni = 0; ni < 8; ni++)
        acc[mi][ni] = __builtin_amdgcn_mfma_f32_16x16x32_bf16(af[mi], bfr[ni], acc[mi][ni], 0, 0, 0);
    __syncthreads();
    cur ^= 1;
  }
#undef STAGE_F1N

  // epilogue: bias + relu, per-row sum-of-squares, scale, emit bf16
  float bv[8];
  #pragma unroll
  for(int ni = 0; ni < 8; ni++) bv[ni] = bias[wc + ni * 16 + (lane & 15)];
  float p[2][4];
  #pragma unroll
  for(int mi = 0; mi < 2; mi++)
    #pragma unroll
    for(int i = 0; i < 4; i++){
      float s = 0.f;
      #pragma unroll
      for(int ni = 0; ni < 8; ni++){
        float v = fmaxf(acc[mi][ni][i] + bv[ni], 0.f);
        acc[mi][ni][i] = v;
        s += v * v;
      }
      p[mi][i] = s;
    }
  // reduce across the 16 col-lanes of each row
  #pragma unroll
  for(int o = 1; o < 16; o <<= 1)
    #pragma unroll
    for(int mi = 0; mi < 2; mi++)
      #pragma unroll
      for(int i = 0; i < 4; i++)
        p[mi][i] += __shfl_xor(p[mi][i], o, 64);
  if((lane & 15) == 0){
    int g = lane >> 4;
    #pragma unroll
    for(int mi = 0; mi < 2; mi++)
      #pragma unroll
      for(int i = 0; i < 4; i++)
        ssq_p[wcol][wr + mi * 16 + g * 4 + i] = p[mi][i];
  }
  __syncthreads();
  if(tid < 64){
    float s = ssq_p[0][tid] + ssq_p[1][tid] + ssq_p[2][tid] + ssq_p[3][tid];
    scale_s[tid] = 1.0f / fmaxf(sqrtf(s), 1e-12f);
  }
  __syncthreads();
  #pragma unroll
  for(int mi = 0; mi < 2; mi++)
    #pragma unroll
    for(int i = 0; i < 4; i++){
      int rt = wr + mi * 16 + (lane >> 4) * 4 + i;
      float sc = scale_s[rt];
      #pragma unroll
      for(int ni = 0; ni < 8; ni++)
        XN[(size_t)(bm0 + rt) * 512 + wc + ni * 16 + (lane & 15)] = f2b(acc[mi][ni][i] * sc);
    }
}

// ------ fused logits GEMM + cluster softmax + transpose -> AT[b][k][n] ---------
// Block = 64 n-rows x 128 k-cols (all 64 real clusters live in the wc=0 waves)
// -> softmax over k is block-local. Removes the LG round-trip (16 MB) and the
// separate softmax kernel. Transpose write via [64][65] LDS (softmax_t pattern).
__global__ __launch_bounds__(256) void gemm_lgsm(
    const ushort* __restrict__ A, const ushort* __restrict__ B,
    const float* __restrict__ bias, float* __restrict__ at)
{
  const int K = 512;
  __shared__ __align__(16) ushort As[2][64 * 32];    // 2 x 4 KB
  __shared__ __align__(16) ushort Bs[2][128 * 32];   // 2 x 8 KB
  __shared__ float as_[64][65];
  const int tid  = threadIdx.x;
  const int lane = tid & 63, wid = tid >> 6;
  const int bm0 = blockIdx.x * 64;
  const int wr = (wid >> 1) * 32, wc = (wid & 1) * 64;

  const int slot = (tid & 3) ^ ((tid >> 3) & 3);
  const ushort* ag = A + (size_t)(bm0 + (tid >> 2)) * K + slot * 8;
  const ushort* bg = B + (size_t)(tid >> 2) * K + slot * 8;

  f32x4 acc[2][4];
  #pragma unroll
  for(int i = 0; i < 2; i++)
    #pragma unroll
    for(int j = 0; j < 4; j++) acc[i][j] = (f32x4){0.f, 0.f, 0.f, 0.f};

  const int arow = lane & 15;
  const int khalf = lane >> 4;

  gload_lds16(ag,          &As[0][tid * 8]);
  gload_lds16(bg,          &Bs[0][tid * 8]);
  gload_lds16(bg + 64 * K, &Bs[0][2048 + tid * 8]);
  __syncthreads();

  int cur = 0;
  for(int ks = 0; ks < 16; ++ks){
    if(ks + 1 < 16){
      const ushort* agn = ag + (ks + 1) * 32;
      const ushort* bgn = bg + (ks + 1) * 32;
      gload_lds16(agn,          &As[cur ^ 1][tid * 8]);
      gload_lds16(bgn,          &Bs[cur ^ 1][tid * 8]);
      gload_lds16(bgn + 64 * K, &Bs[cur ^ 1][2048 + tid * 8]);
    }
    bf16x8 af[2], bfr[4];
    #pragma unroll
    for(int mi = 0; mi < 2; mi++){
      int r = wr + mi * 16 + arow;
      af[mi] = *(const bf16x8*)&As[cur][r * 32 + ((khalf ^ ((r >> 1) & 3)) * 8)];
    }
    #pragma unroll
    for(int ni = 0; ni < 4; ni++){
      int r = wc + ni * 16 + arow;
      bfr[ni] = *(const bf16x8*)&Bs[cur][r * 32 + ((khalf ^ ((r >> 1) & 3)) * 8)];
    }
    #pragma unroll
    for(int mi = 0; mi < 2; mi++)
      #pragma unroll
      for(int ni = 0; ni < 4; ni++)
        acc[mi][ni] = __builtin_amdgcn_mfma_f32_16x16x32_bf16(af[mi], bfr[ni], acc[mi][ni], 0, 0, 0);
    __syncthreads();
    cur ^= 1;
  }

  // epilogue: bias, softmax over the 64 real clusters (wc==0 waves only)
  if((wid & 1) == 0){
    #pragma unroll
    for(int ni = 0; ni < 4; ni++){
      float bvv = bias[ni * 16 + (lane & 15)];
      #pragma unroll
      for(int mi = 0; mi < 2; mi++)
        #pragma unroll
        for(int i = 0; i < 4; i++) acc[mi][ni][i] += bvv;
    }
    #pragma unroll
    for(int mi = 0; mi < 2; mi++)
      #pragma unroll
      for(int i = 0; i < 4; i++){
        int row = wr + mi * 16 + (lane >> 4) * 4 + i;
        float m = fmaxf(fmaxf(acc[mi][0][i], acc[mi][1][i]),
                        fmaxf(acc[mi][2][i], acc[mi][3][i]));
        #pragma unroll
        for(int o = 1; o < 16; o <<= 1) m = fmaxf(m, __shfl_xor(m, o, 64));
        float e[4], s = 0.f;
        #pragma unroll
        for(int ni = 0; ni < 4; ni++){ e[ni] = __expf(acc[mi][ni][i] - m); s += e[ni]; }
        #pragma unroll
        for(int o = 1; o < 16; o <<= 1) s += __shfl_xor(s, o, 64);
        float inv = 1.0f / s;
        #pragma unroll
        for(int ni = 0; ni < 4; ni++)
          as_[row][ni * 16 + (lane & 15)] = e[ni] * inv;
      }
  }
  __syncthreads();

  // transpose write: at[b][k][n0+nl]
  const int b = bm0 >> 10, n0 = bm0 & 1023;
  const int nl = tid & 63, kq = tid >> 6;
  #pragma unroll
  for(int q = 0; q < 16; q++){
    int k = kq * 16 + q;
    at[((size_t)b * 64 + k) * 1024 + n0 + nl] = as_[nl][k];
  }
}

// ------------- VLAD aggregate + intra-normalize -> bf16, plus slice sumsq ------
__global__ __launch_bounds__(512) void vlad_k(const float* __restrict__ at, const ushort* __restrict__ xn,
                                              const float* __restrict__ cent,
                                              ushort* __restrict__ vlb, float* __restrict__ ssq){
  __shared__ float a4[4][1024];
  __shared__ float asum_s[4];
  __shared__ float red[8][4];
  __shared__ float scale_s[4];
  __shared__ float ssq_s[4];
  int tid = threadIdx.x, lane = tid & 63, wid = tid >> 6;
  int b = blockIdx.x, k0 = blockIdx.y * 4;
  #pragma unroll
  for(int u = 0; u < 2; u++){
    int idx = tid * 8 + u * 4;
    int j = idx >> 10, n = idx & 1023;
    *(float4*)&a4[j][n] = *(const float4*)&at[((size_t)b * 64 + k0 + j) * 1024 + n];
  }
  __syncthreads();
  if(wid < 4){
    float p = 0;
    for(int t = lane; t < 1024; t += 64) p += a4[wid][t];
    p = wredsum(p);
    if(lane == 0) asum_s[wid] = p;
  }
  __syncthreads();
  int h = tid;
  const ushort* xb = xn + (size_t)b * 1024 * 512 + h;
  float acc[4] = {0, 0, 0, 0};
  for(int n0 = 0; n0 < 1024; n0 += 8){
    float xv[8];
    #pragma unroll
    for(int u = 0; u < 8; u++) xv[u] = b2f(xb[(size_t)(n0 + u) * 512]);
    #pragma unroll
    for(int j = 0; j < 4; j++){
      float4 alo = *(const float4*)&a4[j][n0];
      float4 ahi = *(const float4*)&a4[j][n0 + 4];
      acc[j] += alo.x * xv[0] + alo.y * xv[1] + alo.z * xv[2] + alo.w * xv[3]
              + ahi.x * xv[4] + ahi.y * xv[5] + ahi.z * xv[6] + ahi.w * xv[7];
    }
  }
  float vl[4];
  #pragma unroll
  for(int j = 0; j < 4; j++)
    vl[j] = acc[j] - asum_s[j] * cent[(size_t)(k0 + j) * 512 + h];
  #pragma unroll
  for(int j = 0; j < 4; j++){
    float s = wredsum(vl[j] * vl[j]);
    if(lane == 0) red[wid][j] = s;
  }
  __syncthreads();
  if(tid < 4){
    float s = 0;
    #pragma unroll
    for(int w = 0; w < 8; w++) s += red[w][tid];
    float sc = 1.0f / fmaxf(sqrtf(s), 1e-12f);
    scale_s[tid] = sc;
    ssq_s[tid] = s * sc * sc;
  }
  __syncthreads();
  if(tid == 0) ssq[b * 16 + blockIdx.y] = ssq_s[0] + ssq_s[1] + ssq_s[2] + ssq_s[3];
  #pragma unroll
  for(int j = 0; j < 4; j++)
    vlb[(size_t)b * 32768 + (size_t)(k0 + j) * 512 + h] = f2b(vl[j] * scale_s[j]);
}

// ------------- fc2 via MFMA, dbuf staging, K-split 128 (4 blocks/CU) -----------
__global__ __launch_bounds__(256) void fc2_mfma(const float* __restrict__ W,
                                                const ushort* __restrict__ vlb,
                                                float* __restrict__ part){
  __shared__ __align__(16) float Bs[2][128 * 32];   // 2 x 16 KB, XOR-swizzled
  const int tid = threadIdx.x, lane = tid & 63, wid = tid >> 6;
  const int c0 = blockIdx.x * 128;
  const int kc = blockIdx.y;                      // 128 chunks of 256 k
  const size_t kbase = (size_t)kc * 256;

  const int srow = tid >> 3;                     // 0..31
  const int seg  = tid & 7;                      // 16B slot
  f32x4 acc0 = (f32x4){0.f,0.f,0.f,0.f};
  f32x4 acc1 = (f32x4){0.f,0.f,0.f,0.f};

  const int arow = lane & 15;
  const int khalf = lane >> 4;
  const int cRow0 = wid * 32 + (lane & 15);
  const int cRow1 = cRow0 + 16;

  #pragma unroll
  for(int pass = 0; pass < 4; ++pass){
    int row = pass * 32 + srow;
    const char* src = (const char*)W + (size_t)(c0 + row) * 131072
                      + kbase * 4 + ((seg ^ (row & 7)) * 16);
    gload_lds16(src, (char*)&Bs[0][0] + row * 128 + seg * 16);
  }
  __syncthreads();

  int cur = 0;
  for(int ks = 0; ks < 8; ++ks){
    if(ks + 1 < 8){
      #pragma unroll
      for(int pass = 0; pass < 4; ++pass){
        int row = pass * 32 + srow;
        const char* src = (const char*)W + (size_t)(c0 + row) * 131072
                          + (kbase + (ks + 1) * 32) * 4 + ((seg ^ (row & 7)) * 16);
        gload_lds16(src, (char*)&Bs[cur ^ 1][0] + row * 128 + seg * 16);
      }
    }
    bf16x8 af = *(const bf16x8*)((const char*)vlb + (size_t)arow * 65536
                                 + (kbase + ks * 32 + khalf * 8) * 2);
    int t0 = khalf * 2;
    const char* bsc = (const char*)&Bs[cur][0];
    float4 b00 = *(const float4*)(bsc + cRow0 * 128 + ((t0     ^ (cRow0 & 7)) * 16));
    float4 b01 = *(const float4*)(bsc + cRow0 * 128 + (((t0+1) ^ (cRow0 & 7)) * 16));
    float4 b10 = *(const float4*)(bsc + cRow1 * 128 + ((t0     ^ (cRow1 & 7)) * 16));
    float4 b11 = *(const float4*)(bsc + cRow1 * 128 + (((t0+1) ^ (cRow1 & 7)) * 16));
    bf16x8 bf0 = cvt8(b00, b01);
    bf16x8 bf1 = cvt8(b10, b11);

    acc0 = __builtin_amdgcn_mfma_f32_16x16x32_bf16(af, bf0, acc0, 0, 0, 0);
    acc1 = __builtin_amdgcn_mfma_f32_16x16x32_bf16(af, bf1, acc1, 0, 0, 0);
    __syncthreads();
    cur ^= 1;
  }

  #pragma unroll
  for(int i = 0; i < 4; ++i){
    int b = (lane >> 4) * 4 + i;
    int d0 = c0 + wid * 32 + (lane & 15);
    part[((size_t)kc * 16 + b) * 1024 + d0]      = acc0[i];
    part[((size_t)kc * 16 + b) * 1024 + d0 + 16] = acc1[i];
  }
}

// ------------- final: 4-way k-split + LDS reduce (256 blocks) ------------------
__global__ __launch_bounds__(256) void fin(const float* __restrict__ part, const float* __restrict__ ssq,
                                           const float* __restrict__ b2, float* __restrict__ out){
  __shared__ float red[4][64];
  int lane = threadIdx.x & 63, wq = threadIdx.x >> 6;
  int o = blockIdx.x * 64 + lane;             // 0..16383
  int b = o >> 10, d = o & 1023;
  float s = 0;
  #pragma unroll
  for(int i = 0; i < 32; i++){
    int t = wq * 32 + i;
    s += part[((size_t)t * 16 + b) * 1024 + d];
  }
  red[wq][lane] = s;
  __syncthreads();
  if(wq == 0){
    float g = 0;
    #pragma unroll
    for(int kg = 0; kg < 16; kg++) g += ssq[b * 16 + kg];
    float gsv = 1.0f / fmaxf(sqrtf(g), 1e-12f);
    float tot = red[0][lane] + red[1][lane] + red[2][lane] + red[3][lane];
    out[o] = fmaxf(gsv * tot + b2[d], 0.0f);
  }
}

extern "C" void kernel_launch(void* const* d_in, const int* in_sizes, int n_in,
                              void* d_out, int out_size, void* d_ws, size_t ws_size,
                              hipStream_t stream){
  const float* X    = (const float*)d_in[0];
  const float* W1   = (const float*)d_in[1];
  const float* B1   = (const float*)d_in[2];
  const float* CW   = (const float*)d_in[3];
  const float* CB   = (const float*)d_in[4];
  const float* CENT = (const float*)d_in[5];
  const float* W2   = (const float*)d_in[6];
  const float* B2   = (const float*)d_in[7];
  float* out = (float*)d_out;
  char* ws = (char*)d_ws;

  ushort* W1b  = (ushort*)(ws + 0);            //  1,048,576
  ushort* CWb  = (ushort*)(ws + 1048576);      //    131,072
  float*  CBp  = (float*) (ws + 1179648);      //        512
  ushort* XN   = (ushort*)(ws + 1180160);      // 16,777,216
  float*  AT   = (float*) (ws + 17957376);     //  4,194,304
  ushort* VLb  = (ushort*)(ws + 22151680);     //  1,048,576 (bf16 vlad)
  float*  SSQ  = (float*) (ws + 23200256);     //      1,024
  float*  PART = (float*) (ws + 23201280);     //  8,388,608

  // prep: W1 cvt + conv_w pad/cvt + conv_b pad (one launch)
  prep<<<769, 256, 0, stream>>>(W1, CW, CB, W1b, CWb, CBp);
  // fused fc1 + bias + relu + row-L2norm -> XN bf16
  fc1n<<<256, 512, 0, stream>>>(X, W1b, B1, XN);
  // fused logits GEMM + softmax over clusters + transpose -> AT[b][k][n]
  gemm_lgsm<<<256, 256, 0, stream>>>(XN, CWb, CBp, AT);
  // VLAD + intra-norm -> VLb bf16 + slice sumsq
  vlad_k<<<dim3(16, 16), 512, 0, stream>>>(AT, XN, CENT, VLb, SSQ);
  // fc2: MFMA, dbuf staging, K-split 128 -> 1024 blocks (4/CU)
  fc2_mfma<<<dim3(8, 128), 256, 0, stream>>>(W2, VLb, PART);
  // final: gscale folded in; 4-way k-split + LDS reduce
  fin<<<256, 256, 0, stream>>>(PART, SSQ, B2, out);
}

// Round 7
// 118.598 us; speedup vs baseline: 1.5567x; 1.2335x over previous
//
#include <hip/hip_runtime.h>
#include <hip/hip_bf16.h>

typedef __bf16  bf16x8 __attribute__((ext_vector_type(8)));
typedef float   f32x4  __attribute__((ext_vector_type(4)));

#define DEV __device__ __forceinline__

DEV ushort f2b(float f){
  union { float f; unsigned u; } c; c.f = f;
  unsigned u = c.u;
  unsigned r = (u + 0x7FFFu + ((u >> 16) & 1u)) >> 16;
  return (ushort)r;
}
DEV float b2f(ushort h){
  union { unsigned u; float f; } c; c.u = ((unsigned)h) << 16;
  return c.f;
}
DEV void gload_lds16(const void* g, void* l){
  __builtin_amdgcn_global_load_lds(
      (const __attribute__((address_space(1))) void*)g,
      (__attribute__((address_space(3))) void*)l,
      16, 0, 0);
}
DEV bf16x8 cvt8(float4 a0, float4 a1){
  bf16x8 t;
  t[0]=(__bf16)a0.x; t[1]=(__bf16)a0.y; t[2]=(__bf16)a0.z; t[3]=(__bf16)a0.w;
  t[4]=(__bf16)a1.x; t[5]=(__bf16)a1.y; t[6]=(__bf16)a1.z; t[7]=(__bf16)a1.w;
  return t;
}

// ---------------- prep: W1 f32->bf16, conv_w pad+cvt, conv_b pad --------------
__global__ void prep(const float* __restrict__ W1, const float* __restrict__ CW,
                     const float* __restrict__ CB,
                     ushort* __restrict__ W1b, ushort* __restrict__ CWb,
                     float* __restrict__ CBp){
  int bid = blockIdx.x, tid = threadIdx.x;
  if(bid < 512){
    int i = bid * 256 + tid;          // float4 index, 131072 total
    float4 f = ((const float4*)W1)[i];
    ushort4 o; o.x = f2b(f.x); o.y = f2b(f.y); o.z = f2b(f.z); o.w = f2b(f.w);
    ((ushort4*)W1b)[i] = o;
  } else if(bid < 768){
    int i = (bid - 512) * 256 + tid;  // 0..65535
    int r = i >> 9;
    CWb[i] = (r < 64) ? f2b(CW[i]) : (ushort)0;
  } else {
    if(tid < 128) CBp[tid] = (tid < 64) ? CB[tid] : 0.0f;
  }
}

// ------- fc1n: fused fc1 GEMM (64x512) + bias + relu + L2norm -> XN & XNT ------
// 512 threads / 8 waves (2 row-waves x 4 col-waves; wave tile 32x128).
// Adds XNT[b][h][n] bf16 output via LDS transpose (Tb[512][66], aliased over
// the dead Af/Bs staging buffers after the K-loop's final barrier).
__global__ __launch_bounds__(512) void fc1n(
    const float* __restrict__ A, const ushort* __restrict__ B,
    const float* __restrict__ bias, ushort* __restrict__ XN,
    ushort* __restrict__ XNT)
{
  const int K = 1024;
  // smem carve: Af[2] = smem + buf*8192 (float[64*32] each, 16KB total)
  //             Bs[2] = smem + 16384 + buf*32768 (ushort[512*32] each, 64KB)
  //             Tb (epilogue) = (ushort*)smem, [512][66] = 67.6KB
  __shared__ __align__(16) char smem[81920];
  __shared__ float ssq_p[4][64];
  __shared__ float scale_s[64];
  const int tid = threadIdx.x, lane = tid & 63, wid = tid >> 6;
  const int bm0 = blockIdx.x * 64;
  const int wr = (wid >> 2) * 32;          // 0 / 32
  const int wc = (wid & 3) * 128;          // 0 / 128 / 256 / 384
  const int wcol = wid & 3;

  // A staging: 64 rows x 128 B -> 512 loads, 1/thread
  const int srow = tid >> 3;               // 0..63
  const int sseg = tid & 7;
  const char* asrc = (const char*)A + (size_t)(bm0 + srow) * 4096
                     + (sseg ^ (srow & 7)) * 16;
  // B staging: 512 rows x 64 B -> 2048 loads, 4/thread (rows tid>>2 + 128p)
  const int bslot = (tid & 3) ^ ((tid >> 3) & 3);   // ((row+128p)>>1)&3 invariant
  const ushort* bg = B + (size_t)(tid >> 2) * K + bslot * 8;

  f32x4 acc[2][8];
  #pragma unroll
  for(int i = 0; i < 2; i++)
    #pragma unroll
    for(int j = 0; j < 8; j++) acc[i][j] = (f32x4){0.f, 0.f, 0.f, 0.f};

  const int arow = lane & 15;
  const int khalf = lane >> 4;

#define STAGE_F1N(buf, kb) do { \
    gload_lds16(asrc + (kb), smem + (buf) * 8192 + tid * 16); \
    const ushort* bs_ = bg + ((kb) >> 2); \
    char* bd_ = smem + 16384 + (buf) * 32768 + tid * 16; \
    gload_lds16(bs_,           bd_); \
    gload_lds16(bs_ + 128 * K, bd_ + 8192); \
    gload_lds16(bs_ + 256 * K, bd_ + 16384); \
    gload_lds16(bs_ + 384 * K, bd_ + 24576); \
  } while(0)

  STAGE_F1N(0, 0);
  __syncthreads();

  int cur = 0;
  for(int ks = 0; ks < 32; ++ks){
    if(ks + 1 < 32) STAGE_F1N(cur ^ 1, (ks + 1) * 128);
    bf16x8 af[2], bfr[8];
    #pragma unroll
    for(int mi = 0; mi < 2; mi++){
      int r = wr + mi * 16 + arow;
      const char* base = smem + cur * 8192 + r * 128;
      float4 a0 = *(const float4*)(base + (((khalf * 2)     ^ (r & 7)) * 16));
      float4 a1 = *(const float4*)(base + (((khalf * 2 + 1) ^ (r & 7)) * 16));
      af[mi] = cvt8(a0, a1);
    }
    #pragma unroll
    for(int ni = 0; ni < 8; ni++){
      int r = wc + ni * 16 + arow;
      bfr[ni] = *(const bf16x8*)(smem + 16384 + cur * 32768
                                 + r * 64 + ((khalf ^ ((r >> 1) & 3)) * 16));
    }
    #pragma unroll
    for(int mi = 0; mi < 2; mi++)
      #pragma unroll
      for(int ni = 0; ni < 8; ni++)
        acc[mi][ni] = __builtin_amdgcn_mfma_f32_16x16x32_bf16(af[mi], bfr[ni], acc[mi][ni], 0, 0, 0);
    __syncthreads();
    cur ^= 1;
  }
#undef STAGE_F1N

  // epilogue: bias + relu, per-row sum-of-squares, scale
  float bv[8];
  #pragma unroll
  for(int ni = 0; ni < 8; ni++) bv[ni] = bias[wc + ni * 16 + (lane & 15)];
  float p[2][4];
  #pragma unroll
  for(int mi = 0; mi < 2; mi++)
    #pragma unroll
    for(int i = 0; i < 4; i++){
      float s = 0.f;
      #pragma unroll
      for(int ni = 0; ni < 8; ni++){
        float v = fmaxf(acc[mi][ni][i] + bv[ni], 0.f);
        acc[mi][ni][i] = v;
        s += v * v;
      }
      p[mi][i] = s;
    }
  #pragma unroll
  for(int o = 1; o < 16; o <<= 1)
    #pragma unroll
    for(int mi = 0; mi < 2; mi++)
      #pragma unroll
      for(int i = 0; i < 4; i++)
        p[mi][i] += __shfl_xor(p[mi][i], o, 64);
  if((lane & 15) == 0){
    int g = lane >> 4;
    #pragma unroll
    for(int mi = 0; mi < 2; mi++)
      #pragma unroll
      for(int i = 0; i < 4; i++)
        ssq_p[wcol][wr + mi * 16 + g * 4 + i] = p[mi][i];
  }
  __syncthreads();
  if(tid < 64){
    float s = ssq_p[0][tid] + ssq_p[1][tid] + ssq_p[2][tid] + ssq_p[3][tid];
    scale_s[tid] = 1.0f / fmaxf(sqrtf(s), 1e-12f);
  }
  __syncthreads();

  // write XN [n][h] + stage transpose into Tb[h][66]
  ushort* Tb = (ushort*)smem;
  #pragma unroll
  for(int mi = 0; mi < 2; mi++)
    #pragma unroll
    for(int i = 0; i < 4; i++){
      int rt = wr + mi * 16 + (lane >> 4) * 4 + i;
      float sc = scale_s[rt];
      #pragma unroll
      for(int ni = 0; ni < 8; ni++){
        int h = wc + ni * 16 + (lane & 15);
        ushort v = f2b(acc[mi][ni][i] * sc);
        XN[(size_t)(bm0 + rt) * 512 + h] = v;
        Tb[h * 66 + rt] = v;
      }
    }
  __syncthreads();
  // XNT[b][h][n0b + 0..63]: thread tid owns h-row tid
  {
    const int bb = bm0 >> 10, n0b = bm0 & 1023;
    const char* tb = (const char*)smem + tid * 132;   // 4B-aligned
    unsigned tmp[32];
    #pragma unroll
    for(int j = 0; j < 32; j++) tmp[j] = *(const unsigned*)(tb + j * 4);
    ushort* dst = XNT + ((size_t)bb * 512 + tid) * 1024 + n0b;
    #pragma unroll
    for(int u = 0; u < 8; u++){
      uint4 w; w.x = tmp[u*4]; w.y = tmp[u*4+1]; w.z = tmp[u*4+2]; w.w = tmp[u*4+3];
      *(uint4*)(dst + u * 8) = w;
    }
  }
}

// ------ fused logits GEMM + cluster softmax -> AThi/ATlo[b][k][n] bf16 ---------
// Block = 64 n-rows x 128 k-cols; softmax over k block-local. Softmax weights
// written as bf16 hi/lo pair (a = hi + lo to ~2^-18) for the MFMA VLAD.
__global__ __launch_bounds__(256) void gemm_lgsm(
    const ushort* __restrict__ A, const ushort* __restrict__ B,
    const float* __restrict__ bias,
    ushort* __restrict__ AThi, ushort* __restrict__ ATlo)
{
  const int K = 512;
  __shared__ __align__(16) ushort As[2][64 * 32];    // 2 x 4 KB
  __shared__ __align__(16) ushort Bs[2][128 * 32];   // 2 x 8 KB
  __shared__ float as_[64][65];
  const int tid  = threadIdx.x;
  const int lane = tid & 63, wid = tid >> 6;
  const int bm0 = blockIdx.x * 64;
  const int wr = (wid >> 1) * 32, wc = (wid & 1) * 64;

  const int slot = (tid & 3) ^ ((tid >> 3) & 3);
  const ushort* ag = A + (size_t)(bm0 + (tid >> 2)) * K + slot * 8;
  const ushort* bg = B + (size_t)(tid >> 2) * K + slot * 8;

  f32x4 acc[2][4];
  #pragma unroll
  for(int i = 0; i < 2; i++)
    #pragma unroll
    for(int j = 0; j < 4; j++) acc[i][j] = (f32x4){0.f, 0.f, 0.f, 0.f};

  const int arow = lane & 15;
  const int khalf = lane >> 4;

  gload_lds16(ag,          &As[0][tid * 8]);
  gload_lds16(bg,          &Bs[0][tid * 8]);
  gload_lds16(bg + 64 * K, &Bs[0][2048 + tid * 8]);
  __syncthreads();

  int cur = 0;
  for(int ks = 0; ks < 16; ++ks){
    if(ks + 1 < 16){
      const ushort* agn = ag + (ks + 1) * 32;
      const ushort* bgn = bg + (ks + 1) * 32;
      gload_lds16(agn,          &As[cur ^ 1][tid * 8]);
      gload_lds16(bgn,          &Bs[cur ^ 1][tid * 8]);
      gload_lds16(bgn + 64 * K, &Bs[cur ^ 1][2048 + tid * 8]);
    }
    bf16x8 af[2], bfr[4];
    #pragma unroll
    for(int mi = 0; mi < 2; mi++){
      int r = wr + mi * 16 + arow;
      af[mi] = *(const bf16x8*)&As[cur][r * 32 + ((khalf ^ ((r >> 1) & 3)) * 8)];
    }
    #pragma unroll
    for(int ni = 0; ni < 4; ni++){
      int r = wc + ni * 16 + arow;
      bfr[ni] = *(const bf16x8*)&Bs[cur][r * 32 + ((khalf ^ ((r >> 1) & 3)) * 8)];
    }
    #pragma unroll
    for(int mi = 0; mi < 2; mi++)
      #pragma unroll
      for(int ni = 0; ni < 4; ni++)
        acc[mi][ni] = __builtin_amdgcn_mfma_f32_16x16x32_bf16(af[mi], bfr[ni], acc[mi][ni], 0, 0, 0);
    __syncthreads();
    cur ^= 1;
  }

  // epilogue: bias, softmax over the 64 real clusters (wc==0 waves only)
  if((wid & 1) == 0){
    #pragma unroll
    for(int ni = 0; ni < 4; ni++){
      float bvv = bias[ni * 16 + (lane & 15)];
      #pragma unroll
      for(int mi = 0; mi < 2; mi++)
        #pragma unroll
        for(int i = 0; i < 4; i++) acc[mi][ni][i] += bvv;
    }
    #pragma unroll
    for(int mi = 0; mi < 2; mi++)
      #pragma unroll
      for(int i = 0; i < 4; i++){
        int row = wr + mi * 16 + (lane >> 4) * 4 + i;
        float m = fmaxf(fmaxf(acc[mi][0][i], acc[mi][1][i]),
                        fmaxf(acc[mi][2][i], acc[mi][3][i]));
        #pragma unroll
        for(int o = 1; o < 16; o <<= 1) m = fmaxf(m, __shfl_xor(m, o, 64));
        float e[4], s = 0.f;
        #pragma unroll
        for(int ni = 0; ni < 4; ni++){ e[ni] = __expf(acc[mi][ni][i] - m); s += e[ni]; }
        #pragma unroll
        for(int o = 1; o < 16; o <<= 1) s += __shfl_xor(s, o, 64);
        float inv = 1.0f / s;
        #pragma unroll
        for(int ni = 0; ni < 4; ni++)
          as_[row][ni * 16 + (lane & 15)] = e[ni] * inv;
      }
  }
  __syncthreads();

  // hi/lo transposed write: AT*[b][k][n0+nl]
  const int b = bm0 >> 10, n0 = bm0 & 1023;
  const int nl = tid & 63, kq = tid >> 6;
  #pragma unroll
  for(int q = 0; q < 16; q++){
    int k = kq * 16 + q;
    float a = as_[nl][k];
    ushort hi = f2b(a);
    float lo = a - b2f(hi);
    size_t idx = ((size_t)b * 64 + k) * 1024 + n0 + nl;
    AThi[idx] = hi;
    ATlo[idx] = f2b(lo);
  }
}

// ---- vlad_mfma: vlad[b][k][h] = Sum_n a*xn via MFMA, + asum corr + intra-norm -
// Grid (16 b, 4 kg). Block 512 thr / 8 waves; tile 16k x 512h, K=1024 n.
// a = AThi + ATlo (bf16 hi/lo, f32-exact); asum via ones-operand MFMA (exact).
// Epilogue: vl = acc - asum*cent; cross-wave ssq; VLb bf16 + SSQ (fin contract).
__global__ __launch_bounds__(512) void vlad_mfma(
    const ushort* __restrict__ AThi, const ushort* __restrict__ ATlo,
    const ushort* __restrict__ XNT, const float* __restrict__ cent,
    ushort* __restrict__ vlb, float* __restrict__ ssq)
{
  __shared__ __align__(16) ushort Ah[2][16 * 32];    // 2 x 1 KB
  __shared__ __align__(16) ushort Al[2][16 * 32];    // 2 x 1 KB
  __shared__ __align__(16) ushort Xs[2][512 * 32];   // 2 x 32 KB
  __shared__ float red[8][16];
  __shared__ float scale_s[16], ssqn_s[16];
  const int tid = threadIdx.x, lane = tid & 63, wid = tid >> 6;
  const int b = blockIdx.x, kg = blockIdx.y;
  const int k0 = kg * 16;
  const int hw = wid;                        // h-base = hw*64
  const int arow = lane & 15, khalf = lane >> 4;

  // Xs staging: u=0..3, seg = u*512+tid -> row = u*128 + (tid>>2), slot = tid&3
  const int xslot = (tid & 3) ^ ((tid >> 3) & 3);
  const ushort* xg = XNT + ((size_t)b * 512 + (tid >> 2)) * 1024 + xslot * 8;
  // A staging: wave0 -> Ah, wave1 -> Al; row = lane>>2 (0..15), slot = lane&3
  const int aslot = (lane & 3) ^ ((lane >> 3) & 3);
  const ushort* ahg = AThi + ((size_t)b * 64 + k0 + (lane >> 2)) * 1024 + aslot * 8;
  const ushort* alg = ATlo + ((size_t)b * 64 + k0 + (lane >> 2)) * 1024 + aslot * 8;

  f32x4 acc[4];
  #pragma unroll
  for(int i = 0; i < 4; i++) acc[i] = (f32x4){0.f, 0.f, 0.f, 0.f};
  f32x4 asum = (f32x4){0.f, 0.f, 0.f, 0.f};
  bf16x8 ones;
  #pragma unroll
  for(int j = 0; j < 8; j++) ones[j] = (__bf16)1.0f;

#define STAGE_VL(buf, n0v) do { \
    char* xd = (char*)&Xs[buf][0] + tid * 16; \
    gload_lds16(xg + (n0v),                xd); \
    gload_lds16(xg + (n0v) + 128 * 1024,   xd + 8192); \
    gload_lds16(xg + (n0v) + 256 * 1024,   xd + 16384); \
    gload_lds16(xg + (n0v) + 384 * 1024,   xd + 24576); \
    if(wid == 0)      gload_lds16(ahg + (n0v), (char*)&Ah[buf][0] + lane * 16); \
    else if(wid == 1) gload_lds16(alg + (n0v), (char*)&Al[buf][0] + lane * 16); \
  } while(0)

  STAGE_VL(0, 0);
  __syncthreads();

  int cur = 0;
  for(int ks = 0; ks < 32; ++ks){
    if(ks + 1 < 32) STAGE_VL(cur ^ 1, (ks + 1) * 32);
    bf16x8 ah, al, bfr[4];
    {
      int sl = khalf ^ ((arow >> 1) & 3);
      ah = *(const bf16x8*)&Ah[cur][arow * 32 + sl * 8];
      al = *(const bf16x8*)&Al[cur][arow * 32 + sl * 8];
    }
    #pragma unroll
    for(int ni = 0; ni < 4; ni++){
      int r = hw * 64 + ni * 16 + arow;
      bfr[ni] = *(const bf16x8*)&Xs[cur][r * 32 + ((khalf ^ ((r >> 1) & 3)) * 8)];
    }
    asum = __builtin_amdgcn_mfma_f32_16x16x32_bf16(ah, ones, asum, 0, 0, 0);
    asum = __builtin_amdgcn_mfma_f32_16x16x32_bf16(al, ones, asum, 0, 0, 0);
    #pragma unroll
    for(int ni = 0; ni < 4; ni++){
      acc[ni] = __builtin_amdgcn_mfma_f32_16x16x32_bf16(ah, bfr[ni], acc[ni], 0, 0, 0);
      acc[ni] = __builtin_amdgcn_mfma_f32_16x16x32_bf16(al, bfr[ni], acc[ni], 0, 0, 0);
    }
    __syncthreads();
    cur ^= 1;
  }
#undef STAGE_VL

  // epilogue: vl = acc - asum*cent; intra-norm per k-row (512 h, cross-wave)
  float vl[4][4];
  #pragma unroll
  for(int ni = 0; ni < 4; ni++)
    #pragma unroll
    for(int i = 0; i < 4; i++){
      int r_ = (lane >> 4) * 4 + i;
      int h = hw * 64 + ni * 16 + (lane & 15);
      vl[ni][i] = acc[ni][i] - asum[i] * cent[(size_t)(k0 + r_) * 512 + h];
    }
  float sq[4];
  #pragma unroll
  for(int i = 0; i < 4; i++){
    float s = 0.f;
    #pragma unroll
    for(int ni = 0; ni < 4; ni++) s += vl[ni][i] * vl[ni][i];
    sq[i] = s;
  }
  #pragma unroll
  for(int o = 1; o < 16; o <<= 1)
    #pragma unroll
    for(int i = 0; i < 4; i++) sq[i] += __shfl_xor(sq[i], o, 64);
  if((lane & 15) == 0){
    #pragma unroll
    for(int i = 0; i < 4; i++) red[hw][(lane >> 4) * 4 + i] = sq[i];
  }
  __syncthreads();
  if(tid < 16){
    float s = 0.f;
    #pragma unroll
    for(int w = 0; w < 8; w++) s += red[w][tid];
    float sc = 1.0f / fmaxf(sqrtf(s), 1e-12f);
    scale_s[tid] = sc;
    ssqn_s[tid] = s * sc * sc;
  }
  __syncthreads();
  if(tid < 4)
    ssq[b * 16 + kg * 4 + tid] = ssqn_s[tid * 4] + ssqn_s[tid * 4 + 1]
                               + ssqn_s[tid * 4 + 2] + ssqn_s[tid * 4 + 3];
  #pragma unroll
  for(int ni = 0; ni < 4; ni++)
    #pragma unroll
    for(int i = 0; i < 4; i++){
      int r_ = (lane >> 4) * 4 + i;
      int h = hw * 64 + ni * 16 + (lane & 15);
      vlb[(size_t)b * 32768 + (size_t)(k0 + r_) * 512 + h] = f2b(vl[ni][i] * scale_s[r_]);
    }
}

// ------------- fc2 via MFMA, dbuf staging, K-split 128 (4 blocks/CU) -----------
__global__ __launch_bounds__(256) void fc2_mfma(const float* __restrict__ W,
                                                const ushort* __restrict__ vlb,
                                                float* __restrict__ part){
  __shared__ __align__(16) float Bs[2][128 * 32];   // 2 x 16 KB, XOR-swizzled
  const int tid = threadIdx.x, lane = tid & 63, wid = tid >> 6;
  const int c0 = blockIdx.x * 128;
  const int kc = blockIdx.y;                      // 128 chunks of 256 k
  const size_t kbase = (size_t)kc * 256;

  const int srow = tid >> 3;                     // 0..31
  const int seg  = tid & 7;                      // 16B slot
  f32x4 acc0 = (f32x4){0.f,0.f,0.f,0.f};
  f32x4 acc1 = (f32x4){0.f,0.f,0.f,0.f};

  const int arow = lane & 15;
  const int khalf = lane >> 4;
  const int cRow0 = wid * 32 + (lane & 15);
  const int cRow1 = cRow0 + 16;

  #pragma unroll
  for(int pass = 0; pass < 4; ++pass){
    int row = pass * 32 + srow;
    const char* src = (const char*)W + (size_t)(c0 + row) * 131072
                      + kbase * 4 + ((seg ^ (row & 7)) * 16);
    gload_lds16(src, (char*)&Bs[0][0] + row * 128 + seg * 16);
  }
  __syncthreads();

  int cur = 0;
  for(int ks = 0; ks < 8; ++ks){
    if(ks + 1 < 8){
      #pragma unroll
      for(int pass = 0; pass < 4; ++pass){
        int row = pass * 32 + srow;
        const char* src = (const char*)W + (size_t)(c0 + row) * 131072
                          + (kbase + (ks + 1) * 32) * 4 + ((seg ^ (row & 7)) * 16);
        gload_lds16(src, (char*)&Bs[cur ^ 1][0] + row * 128 + seg * 16);
      }
    }
    bf16x8 af = *(const bf16x8*)((const char*)vlb + (size_t)arow * 65536
                                 + (kbase + ks * 32 + khalf * 8) * 2);
    int t0 = khalf * 2;
    const char* bsc = (const char*)&Bs[cur][0];
    float4 b00 = *(const float4*)(bsc + cRow0 * 128 + ((t0     ^ (cRow0 & 7)) * 16));
    float4 b01 = *(const float4*)(bsc + cRow0 * 128 + (((t0+1) ^ (cRow0 & 7)) * 16));
    float4 b10 = *(const float4*)(bsc + cRow1 * 128 + ((t0     ^ (cRow1 & 7)) * 16));
    float4 b11 = *(const float4*)(bsc + cRow1 * 128 + (((t0+1) ^ (cRow1 & 7)) * 16));
    bf16x8 bf0 = cvt8(b00, b01);
    bf16x8 bf1 = cvt8(b10, b11);

    acc0 = __builtin_amdgcn_mfma_f32_16x16x32_bf16(af, bf0, acc0, 0, 0, 0);
    acc1 = __builtin_amdgcn_mfma_f32_16x16x32_bf16(af, bf1, acc1, 0, 0, 0);
    __syncthreads();
    cur ^= 1;
  }

  #pragma unroll
  for(int i = 0; i < 4; ++i){
    int b = (lane >> 4) * 4 + i;
    int d0 = c0 + wid * 32 + (lane & 15);
    part[((size_t)kc * 16 + b) * 1024 + d0]      = acc0[i];
    part[((size_t)kc * 16 + b) * 1024 + d0 + 16] = acc1[i];
  }
}

// ------------- final: 4-way k-split + LDS reduce (256 blocks) ------------------
__global__ __launch_bounds__(256) void fin(const float* __restrict__ part, const float* __restrict__ ssq,
                                           const float* __restrict__ b2, float* __restrict__ out){
  __shared__ float red[4][64];
  int lane = threadIdx.x & 63, wq = threadIdx.x >> 6;
  int o = blockIdx.x * 64 + lane;             // 0..16383
  int b = o >> 10, d = o & 1023;
  float s = 0;
  #pragma unroll
  for(int i = 0; i < 32; i++){
    int t = wq * 32 + i;
    s += part[((size_t)t * 16 + b) * 1024 + d];
  }
  red[wq][lane] = s;
  __syncthreads();
  if(wq == 0){
    float g = 0;
    #pragma unroll
    for(int kg = 0; kg < 16; kg++) g += ssq[b * 16 + kg];
    float gsv = 1.0f / fmaxf(sqrtf(g), 1e-12f);
    float tot = red[0][lane] + red[1][lane] + red[2][lane] + red[3][lane];
    out[o] = fmaxf(gsv * tot + b2[d], 0.0f);
  }
}

extern "C" void kernel_launch(void* const* d_in, const int* in_sizes, int n_in,
                              void* d_out, int out_size, void* d_ws, size_t ws_size,
                              hipStream_t stream){
  const float* X    = (const float*)d_in[0];
  const float* W1   = (const float*)d_in[1];
  const float* B1   = (const float*)d_in[2];
  const float* CW   = (const float*)d_in[3];
  const float* CB   = (const float*)d_in[4];
  const float* CENT = (const float*)d_in[5];
  const float* W2   = (const float*)d_in[6];
  const float* B2   = (const float*)d_in[7];
  float* out = (float*)d_out;
  char* ws = (char*)d_ws;

  ushort* W1b  = (ushort*)(ws + 0);            //  1,048,576
  ushort* CWb  = (ushort*)(ws + 1048576);      //    131,072
  float*  CBp  = (float*) (ws + 1179648);      //        512
  ushort* XN   = (ushort*)(ws + 1180160);      // 16,777,216
  ushort* XNT  = (ushort*)(ws + 17957376);     // 16,777,216
  ushort* AThi = (ushort*)(ws + 34734592);     //  2,097,152
  ushort* ATlo = (ushort*)(ws + 36831744);     //  2,097,152
  ushort* VLb  = (ushort*)(ws + 38928896);     //  1,048,576
  float*  SSQ  = (float*) (ws + 39977472);     //      1,024
  float*  PART = (float*) (ws + 39978496);     //  8,388,608

  // prep: W1 cvt + conv_w pad/cvt + conv_b pad (one launch)
  prep<<<769, 256, 0, stream>>>(W1, CW, CB, W1b, CWb, CBp);
  // fused fc1 + bias + relu + row-L2norm -> XN bf16 + XNT bf16 (transposed)
  fc1n<<<256, 512, 0, stream>>>(X, W1b, B1, XN, XNT);
  // fused logits GEMM + softmax -> AThi/ATlo bf16 hi/lo
  gemm_lgsm<<<256, 256, 0, stream>>>(XN, CWb, CBp, AThi, ATlo);
  // VLAD via MFMA (a = hi+lo, asum via ones-MFMA) + intra-norm -> VLb + SSQ
  vlad_mfma<<<dim3(16, 4), 512, 0, stream>>>(AThi, ATlo, XNT, CENT, VLb, SSQ);
  // fc2: MFMA, dbuf staging, K-split 128 -> 1024 blocks (4/CU)
  fc2_mfma<<<dim3(8, 128), 256, 0, stream>>>(W2, VLb, PART);
  // final: gscale folded in; 4-way k-split + LDS reduce
  fin<<<256, 256, 0, stream>>>(PART, SSQ, B2, out);
}

// Round 8
// 110.459 us; speedup vs baseline: 1.6714x; 1.0737x over previous
//
#include <hip/hip_runtime.h>
#include <hip/hip_bf16.h>

typedef __bf16  bf16x8 __attribute__((ext_vector_type(8)));
typedef float   f32x4  __attribute__((ext_vector_type(4)));

#define DEV __device__ __forceinline__

DEV ushort f2b(float f){
  union { float f; unsigned u; } c; c.f = f;
  unsigned u = c.u;
  unsigned r = (u + 0x7FFFu + ((u >> 16) & 1u)) >> 16;
  return (ushort)r;
}
DEV float b2f(ushort h){
  union { unsigned u; float f; } c; c.u = ((unsigned)h) << 16;
  return c.f;
}
DEV float wredsum(float v){
  #pragma unroll
  for(int o = 32; o > 0; o >>= 1) v += __shfl_xor(v, o, 64);
  return v;
}
DEV float wredmax(float v){
  #pragma unroll
  for(int o = 32; o > 0; o >>= 1) v = fmaxf(v, __shfl_xor(v, o, 64));
  return v;
}
DEV void gload_lds16(const void* g, void* l){
  __builtin_amdgcn_global_load_lds(
      (const __attribute__((address_space(1))) void*)g,
      (__attribute__((address_space(3))) void*)l,
      16, 0, 0);
}
DEV bf16x8 cvt8(float4 a0, float4 a1){
  bf16x8 t;
  t[0]=(__bf16)a0.x; t[1]=(__bf16)a0.y; t[2]=(__bf16)a0.z; t[3]=(__bf16)a0.w;
  t[4]=(__bf16)a1.x; t[5]=(__bf16)a1.y; t[6]=(__bf16)a1.z; t[7]=(__bf16)a1.w;
  return t;
}

// ------- prep: W1 f32->bf16, conv_w cvt + PRE-SWIZZLE (seg^=k&7), conv_b ------
__global__ void prep(const float* __restrict__ W1, const float* __restrict__ CW,
                     const float* __restrict__ CB,
                     ushort* __restrict__ W1b, ushort* __restrict__ CWb,
                     float* __restrict__ CBp){
  int bid = blockIdx.x, tid = threadIdx.x;
  if(bid < 512){
    int i = bid * 256 + tid;          // float4 index, 131072 total
    float4 f = ((const float4*)W1)[i];
    ushort4 o; o.x = f2b(f.x); o.y = f2b(f.y); o.z = f2b(f.z); o.w = f2b(f.w);
    ((ushort4*)W1b)[i] = o;
  } else if(bid < 640){
    int i = (bid - 512) * 256 + tid;  // 0..32767 (64 real rows only)
    int k = i >> 9, h = i & 511;
    int seg = h >> 3, pos = h & 7;    // low-3 seg bits XORed -> hits bank field
    CWb[(k << 9) + ((seg ^ (k & 7)) << 3) + pos] = f2b(CW[i]);
  } else {
    if(tid < 128) CBp[tid] = (tid < 64) ? CB[tid] : 0.0f;
  }
}

// -- fc1sm: fc1 GEMM (64x512) + bias/relu/L2norm -> XNT, THEN logits GEMM +
//    softmax + hi/lo AT write, all in one block (grid 256 = 1 block/CU, so
//    LDS up to 160KB is free). XN global buffer eliminated (only consumer
//    was the logits GEMM, now in-LDS via xn_nm).
// smem phases:  main: Af dbuf [0,16K) | Bs dbuf [16K,80K) | Tb [80K,146K)
//               epi:  xn_nm [0,65K)   | CWs [65K,129K)    | as_ [129K,145.2K)
__global__ __launch_bounds__(512) void fc1sm(
    const float* __restrict__ A, const ushort* __restrict__ B,
    const float* __restrict__ bias, const ushort* __restrict__ CWb,
    const float* __restrict__ CBp, ushort* __restrict__ XNT,
    ushort* __restrict__ AThi, ushort* __restrict__ ATlo)
{
  const int K = 1024;
  __shared__ __align__(16) char smem[149504];
  __shared__ float ssq_p[4][64];
  __shared__ float scale_s[64];
  const int tid = threadIdx.x, lane = tid & 63, wid = tid >> 6;
  const int bm0 = blockIdx.x * 64;
  const int wr = (wid >> 2) * 32;          // 0 / 32
  const int wc = (wid & 3) * 128;          // 0 / 128 / 256 / 384
  const int wcol = wid & 3;

  const int srow = tid >> 3;               // 0..63 (A staging)
  const int sseg = tid & 7;
  const char* asrc = (const char*)A + (size_t)(bm0 + srow) * 4096
                     + (sseg ^ (srow & 7)) * 16;
  const int bslot = (tid & 3) ^ ((tid >> 3) & 3);
  const ushort* bg = B + (size_t)(tid >> 2) * K + bslot * 8;

  f32x4 acc[2][8];
  #pragma unroll
  for(int i = 0; i < 2; i++)
    #pragma unroll
    for(int j = 0; j < 8; j++) acc[i][j] = (f32x4){0.f, 0.f, 0.f, 0.f};

  const int arow = lane & 15;
  const int khalf = lane >> 4;

#define STAGE_F1N(buf, kb) do { \
    gload_lds16(asrc + (kb), smem + (buf) * 8192 + tid * 16); \
    const ushort* bs_ = bg + ((kb) >> 2); \
    char* bd_ = smem + 16384 + (buf) * 32768 + tid * 16; \
    gload_lds16(bs_,           bd_); \
    gload_lds16(bs_ + 128 * K, bd_ + 8192); \
    gload_lds16(bs_ + 256 * K, bd_ + 16384); \
    gload_lds16(bs_ + 384 * K, bd_ + 24576); \
  } while(0)

  STAGE_F1N(0, 0);
  __syncthreads();

  int cur = 0;
  for(int ks = 0; ks < 32; ++ks){
    if(ks + 1 < 32) STAGE_F1N(cur ^ 1, (ks + 1) * 128);
    bf16x8 af[2], bfr[8];
    #pragma unroll
    for(int mi = 0; mi < 2; mi++){
      int r = wr + mi * 16 + arow;
      const char* base = smem + cur * 8192 + r * 128;
      float4 a0 = *(const float4*)(base + (((khalf * 2)     ^ (r & 7)) * 16));
      float4 a1 = *(const float4*)(base + (((khalf * 2 + 1) ^ (r & 7)) * 16));
      af[mi] = cvt8(a0, a1);
    }
    #pragma unroll
    for(int ni = 0; ni < 8; ni++){
      int r = wc + ni * 16 + arow;
      bfr[ni] = *(const bf16x8*)(smem + 16384 + cur * 32768
                                 + r * 64 + ((khalf ^ ((r >> 1) & 3)) * 16));
    }
    #pragma unroll
    for(int mi = 0; mi < 2; mi++)
      #pragma unroll
      for(int ni = 0; ni < 8; ni++)
        acc[mi][ni] = __builtin_amdgcn_mfma_f32_16x16x32_bf16(af[mi], bfr[ni], acc[mi][ni], 0, 0, 0);
    __syncthreads();
    cur ^= 1;
  }
#undef STAGE_F1N

  // ---- epilogue 1: bias + relu, row ssq, scale ----
  float bv[8];
  #pragma unroll
  for(int ni = 0; ni < 8; ni++) bv[ni] = bias[wc + ni * 16 + (lane & 15)];
  float p[2][4];
  #pragma unroll
  for(int mi = 0; mi < 2; mi++)
    #pragma unroll
    for(int i = 0; i < 4; i++){
      float s = 0.f;
      #pragma unroll
      for(int ni = 0; ni < 8; ni++){
        float v = fmaxf(acc[mi][ni][i] + bv[ni], 0.f);
        acc[mi][ni][i] = v;
        s += v * v;
      }
      p[mi][i] = s;
    }
  #pragma unroll
  for(int o = 1; o < 16; o <<= 1)
    #pragma unroll
    for(int mi = 0; mi < 2; mi++)
      #pragma unroll
      for(int i = 0; i < 4; i++)
        p[mi][i] += __shfl_xor(p[mi][i], o, 64);
  if((lane & 15) == 0){
    int g = lane >> 4;
    #pragma unroll
    for(int mi = 0; mi < 2; mi++)
      #pragma unroll
      for(int i = 0; i < 4; i++)
        ssq_p[wcol][wr + mi * 16 + g * 4 + i] = p[mi][i];
  }
  __syncthreads();
  if(tid < 64){
    float s = ssq_p[0][tid] + ssq_p[1][tid] + ssq_p[2][tid] + ssq_p[3][tid];
    scale_s[tid] = 1.0f / fmaxf(sqrtf(s), 1e-12f);
  }
  __syncthreads();

  // ---- epilogue 2: scaled bf16 into Tb[h][66] (for XNT) + xn_nm[n][520] ----
  ushort* Tb  = (ushort*)(smem + 81920);
  ushort* xnm = (ushort*)smem;             // over dead staging
  #pragma unroll
  for(int mi = 0; mi < 2; mi++)
    #pragma unroll
    for(int i = 0; i < 4; i++){
      int rt = wr + mi * 16 + (lane >> 4) * 4 + i;
      float sc = scale_s[rt];
      #pragma unroll
      for(int ni = 0; ni < 8; ni++){
        int h = wc + ni * 16 + (lane & 15);
        ushort v = f2b(acc[mi][ni][i] * sc);
        Tb[h * 66 + rt] = v;
        xnm[rt * 520 + h] = v;
      }
    }
  __syncthreads();

  // ---- XNT[b][h][n0+0..63] from Tb ----
  const int bb = bm0 >> 10, n0b = bm0 & 1023;
  {
    const char* tb = (const char*)smem + 81920 + tid * 132;
    unsigned tmp[32];
    #pragma unroll
    for(int j = 0; j < 32; j++) tmp[j] = *(const unsigned*)(tb + j * 4);
    ushort* dst = XNT + ((size_t)bb * 512 + tid) * 1024 + n0b;
    #pragma unroll
    for(int u = 0; u < 8; u++){
      uint4 w; w.x = tmp[u*4]; w.y = tmp[u*4+1]; w.z = tmp[u*4+2]; w.w = tmp[u*4+3];
      *(uint4*)(dst + u * 8) = w;
    }
  }
  __syncthreads();

  // ---- stage CWs (64 rows x 512 h bf16, pre-swizzled source, linear copy) ----
  char* CWs = smem + 66560;                // over dead Tb
  #pragma unroll
  for(int pp = 0; pp < 8; pp++)
    gload_lds16((const char*)CWb + pp * 8192 + tid * 16, CWs + pp * 8192 + tid * 16);
  __syncthreads();

  // ---- logits MFMA: 64n x 64k, K=512h; wave tile 32n x 16k ----
  float* as_ = (float*)(smem + 132096);
  const int nt = (wid >> 2) * 32, kt = (wid & 3) * 16;
  f32x4 acc2[2];
  acc2[0] = (f32x4){0.f,0.f,0.f,0.f};
  acc2[1] = (f32x4){0.f,0.f,0.f,0.f};
  const int kr = kt + arow;
  #pragma unroll
  for(int s = 0; s < 16; ++s){
    bf16x8 a0 = *(const bf16x8*)(smem + (size_t)(nt + arow) * 1040 + s * 64 + khalf * 16);
    bf16x8 a1 = *(const bf16x8*)(smem + (size_t)(nt + 16 + arow) * 1040 + s * 64 + khalf * 16);
    bf16x8 bw = *(const bf16x8*)(CWs + kr * 1024 + (((s * 4 + khalf) ^ (kr & 7)) * 16));
    acc2[0] = __builtin_amdgcn_mfma_f32_16x16x32_bf16(a0, bw, acc2[0], 0, 0, 0);
    acc2[1] = __builtin_amdgcn_mfma_f32_16x16x32_bf16(a1, bw, acc2[1], 0, 0, 0);
  }
  {
    float bv2 = CBp[kt + (lane & 15)];
    #pragma unroll
    for(int mi = 0; mi < 2; mi++)
      #pragma unroll
      for(int i = 0; i < 4; i++)
        as_[(nt + mi * 16 + (lane >> 4) * 4 + i) * 65 + kt + (lane & 15)] = acc2[mi][i] + bv2;
  }
  __syncthreads();

  // ---- softmax over k=64 (8 waves x 8 rows, full-wave reduce) ----
  #pragma unroll
  for(int i = 0; i < 8; i++){
    int rl = wid * 8 + i;
    float l = as_[rl * 65 + lane];
    float m = wredmax(l);
    float e = __expf(l - m);
    float s = wredsum(e);
    as_[rl * 65 + lane] = e / s;
  }
  __syncthreads();

  // ---- hi/lo transposed write: AT*[b][k][n0+nl] ----
  {
    const int nl = tid & 63, kq = tid >> 6;
    #pragma unroll
    for(int q = 0; q < 8; q++){
      int k = kq * 8 + q;
      float a = as_[nl * 65 + k];
      ushort hi = f2b(a);
      float lo = a - b2f(hi);
      size_t idx = ((size_t)bb * 64 + k) * 1024 + n0b + nl;
      AThi[idx] = hi;
      ATlo[idx] = f2b(lo);
    }
  }
}

// ---- vlad_mfma: vlad[b][k][h] = Sum_n a*xn via MFMA, + asum corr + intra-norm -
__global__ __launch_bounds__(512) void vlad_mfma(
    const ushort* __restrict__ AThi, const ushort* __restrict__ ATlo,
    const ushort* __restrict__ XNT, const float* __restrict__ cent,
    ushort* __restrict__ vlb, float* __restrict__ ssq)
{
  __shared__ __align__(16) ushort Ah[2][16 * 32];    // 2 x 1 KB
  __shared__ __align__(16) ushort Al[2][16 * 32];    // 2 x 1 KB
  __shared__ __align__(16) ushort Xs[2][512 * 32];   // 2 x 32 KB
  __shared__ float red[8][16];
  __shared__ float scale_s[16], ssqn_s[16];
  const int tid = threadIdx.x, lane = tid & 63, wid = tid >> 6;
  const int b = blockIdx.x, kg = blockIdx.y;
  const int k0 = kg * 16;
  const int hw = wid;                        // h-base = hw*64
  const int arow = lane & 15, khalf = lane >> 4;

  const int xslot = (tid & 3) ^ ((tid >> 3) & 3);
  const ushort* xg = XNT + ((size_t)b * 512 + (tid >> 2)) * 1024 + xslot * 8;
  const int aslot = (lane & 3) ^ ((lane >> 3) & 3);
  const ushort* ahg = AThi + ((size_t)b * 64 + k0 + (lane >> 2)) * 1024 + aslot * 8;
  const ushort* alg = ATlo + ((size_t)b * 64 + k0 + (lane >> 2)) * 1024 + aslot * 8;

  f32x4 acc[4];
  #pragma unroll
  for(int i = 0; i < 4; i++) acc[i] = (f32x4){0.f, 0.f, 0.f, 0.f};
  f32x4 asum = (f32x4){0.f, 0.f, 0.f, 0.f};
  bf16x8 ones;
  #pragma unroll
  for(int j = 0; j < 8; j++) ones[j] = (__bf16)1.0f;

#define STAGE_VL(buf, n0v) do { \
    char* xd = (char*)&Xs[buf][0] + tid * 16; \
    gload_lds16(xg + (n0v),                xd); \
    gload_lds16(xg + (n0v) + 128 * 1024,   xd + 8192); \
    gload_lds16(xg + (n0v) + 256 * 1024,   xd + 16384); \
    gload_lds16(xg + (n0v) + 384 * 1024,   xd + 24576); \
    if(wid == 0)      gload_lds16(ahg + (n0v), (char*)&Ah[buf][0] + lane * 16); \
    else if(wid == 1) gload_lds16(alg + (n0v), (char*)&Al[buf][0] + lane * 16); \
  } while(0)

  STAGE_VL(0, 0);
  __syncthreads();

  int cur = 0;
  for(int ks = 0; ks < 32; ++ks){
    if(ks + 1 < 32) STAGE_VL(cur ^ 1, (ks + 1) * 32);
    bf16x8 ah, al, bfr[4];
    {
      int sl = khalf ^ ((arow >> 1) & 3);
      ah = *(const bf16x8*)&Ah[cur][arow * 32 + sl * 8];
      al = *(const bf16x8*)&Al[cur][arow * 32 + sl * 8];
    }
    #pragma unroll
    for(int ni = 0; ni < 4; ni++){
      int r = hw * 64 + ni * 16 + arow;
      bfr[ni] = *(const bf16x8*)&Xs[cur][r * 32 + ((khalf ^ ((r >> 1) & 3)) * 8)];
    }
    asum = __builtin_amdgcn_mfma_f32_16x16x32_bf16(ah, ones, asum, 0, 0, 0);
    asum = __builtin_amdgcn_mfma_f32_16x16x32_bf16(al, ones, asum, 0, 0, 0);
    #pragma unroll
    for(int ni = 0; ni < 4; ni++){
      acc[ni] = __builtin_amdgcn_mfma_f32_16x16x32_bf16(ah, bfr[ni], acc[ni], 0, 0, 0);
      acc[ni] = __builtin_amdgcn_mfma_f32_16x16x32_bf16(al, bfr[ni], acc[ni], 0, 0, 0);
    }
    __syncthreads();
    cur ^= 1;
  }
#undef STAGE_VL

  float vl[4][4];
  #pragma unroll
  for(int ni = 0; ni < 4; ni++)
    #pragma unroll
    for(int i = 0; i < 4; i++){
      int r_ = (lane >> 4) * 4 + i;
      int h = hw * 64 + ni * 16 + (lane & 15);
      vl[ni][i] = acc[ni][i] - asum[i] * cent[(size_t)(k0 + r_) * 512 + h];
    }
  float sq[4];
  #pragma unroll
  for(int i = 0; i < 4; i++){
    float s = 0.f;
    #pragma unroll
    for(int ni = 0; ni < 4; ni++) s += vl[ni][i] * vl[ni][i];
    sq[i] = s;
  }
  #pragma unroll
  for(int o = 1; o < 16; o <<= 1)
    #pragma unroll
    for(int i = 0; i < 4; i++) sq[i] += __shfl_xor(sq[i], o, 64);
  if((lane & 15) == 0){
    #pragma unroll
    for(int i = 0; i < 4; i++) red[hw][(lane >> 4) * 4 + i] = sq[i];
  }
  __syncthreads();
  if(tid < 16){
    float s = 0.f;
    #pragma unroll
    for(int w = 0; w < 8; w++) s += red[w][tid];
    float sc = 1.0f / fmaxf(sqrtf(s), 1e-12f);
    scale_s[tid] = sc;
    ssqn_s[tid] = s * sc * sc;
  }
  __syncthreads();
  if(tid < 4)
    ssq[b * 16 + kg * 4 + tid] = ssqn_s[tid * 4] + ssqn_s[tid * 4 + 1]
                               + ssqn_s[tid * 4 + 2] + ssqn_s[tid * 4 + 3];
  #pragma unroll
  for(int ni = 0; ni < 4; ni++)
    #pragma unroll
    for(int i = 0; i < 4; i++){
      int r_ = (lane >> 4) * 4 + i;
      int h = hw * 64 + ni * 16 + (lane & 15);
      vlb[(size_t)b * 32768 + (size_t)(k0 + r_) * 512 + h] = f2b(vl[ni][i] * scale_s[r_]);
    }
}

// ------------- fc2 via MFMA, dbuf staging, K-split 128 (4 blocks/CU) -----------
__global__ __launch_bounds__(256) void fc2_mfma(const float* __restrict__ W,
                                                const ushort* __restrict__ vlb,
                                                float* __restrict__ part){
  __shared__ __align__(16) float Bs[2][128 * 32];   // 2 x 16 KB, XOR-swizzled
  const int tid = threadIdx.x, lane = tid & 63, wid = tid >> 6;
  const int c0 = blockIdx.x * 128;
  const int kc = blockIdx.y;                      // 128 chunks of 256 k
  const size_t kbase = (size_t)kc * 256;

  const int srow = tid >> 3;                     // 0..31
  const int seg  = tid & 7;                      // 16B slot
  f32x4 acc0 = (f32x4){0.f,0.f,0.f,0.f};
  f32x4 acc1 = (f32x4){0.f,0.f,0.f,0.f};

  const int arow = lane & 15;
  const int khalf = lane >> 4;
  const int cRow0 = wid * 32 + (lane & 15);
  const int cRow1 = cRow0 + 16;

  #pragma unroll
  for(int pass = 0; pass < 4; ++pass){
    int row = pass * 32 + srow;
    const char* src = (const char*)W + (size_t)(c0 + row) * 131072
                      + kbase * 4 + ((seg ^ (row & 7)) * 16);
    gload_lds16(src, (char*)&Bs[0][0] + row * 128 + seg * 16);
  }
  __syncthreads();

  int cur = 0;
  for(int ks = 0; ks < 8; ++ks){
    if(ks + 1 < 8){
      #pragma unroll
      for(int pass = 0; pass < 4; ++pass){
        int row = pass * 32 + srow;
        const char* src = (const char*)W + (size_t)(c0 + row) * 131072
                          + (kbase + (ks + 1) * 32) * 4 + ((seg ^ (row & 7)) * 16);
        gload_lds16(src, (char*)&Bs[cur ^ 1][0] + row * 128 + seg * 16);
      }
    }
    bf16x8 af = *(const bf16x8*)((const char*)vlb + (size_t)arow * 65536
                                 + (kbase + ks * 32 + khalf * 8) * 2);
    int t0 = khalf * 2;
    const char* bsc = (const char*)&Bs[cur][0];
    float4 b00 = *(const float4*)(bsc + cRow0 * 128 + ((t0     ^ (cRow0 & 7)) * 16));
    float4 b01 = *(const float4*)(bsc + cRow0 * 128 + (((t0+1) ^ (cRow0 & 7)) * 16));
    float4 b10 = *(const float4*)(bsc + cRow1 * 128 + ((t0     ^ (cRow1 & 7)) * 16));
    float4 b11 = *(const float4*)(bsc + cRow1 * 128 + (((t0+1) ^ (cRow1 & 7)) * 16));
    bf16x8 bf0 = cvt8(b00, b01);
    bf16x8 bf1 = cvt8(b10, b11);

    acc0 = __builtin_amdgcn_mfma_f32_16x16x32_bf16(af, bf0, acc0, 0, 0, 0);
    acc1 = __builtin_amdgcn_mfma_f32_16x16x32_bf16(af, bf1, acc1, 0, 0, 0);
    __syncthreads();
    cur ^= 1;
  }

  #pragma unroll
  for(int i = 0; i < 4; ++i){
    int b = (lane >> 4) * 4 + i;
    int d0 = c0 + wid * 32 + (lane & 15);
    part[((size_t)kc * 16 + b) * 1024 + d0]      = acc0[i];
    part[((size_t)kc * 16 + b) * 1024 + d0 + 16] = acc1[i];
  }
}

// ------------- final: 4-way k-split + LDS reduce (256 blocks) ------------------
__global__ __launch_bounds__(256) void fin(const float* __restrict__ part, const float* __restrict__ ssq,
                                           const float* __restrict__ b2, float* __restrict__ out){
  __shared__ float red[4][64];
  int lane = threadIdx.x & 63, wq = threadIdx.x >> 6;
  int o = blockIdx.x * 64 + lane;             // 0..16383
  int b = o >> 10, d = o & 1023;
  float s = 0;
  #pragma unroll
  for(int i = 0; i < 32; i++){
    int t = wq * 32 + i;
    s += part[((size_t)t * 16 + b) * 1024 + d];
  }
  red[wq][lane] = s;
  __syncthreads();
  if(wq == 0){
    float g = 0;
    #pragma unroll
    for(int kg = 0; kg < 16; kg++) g += ssq[b * 16 + kg];
    float gsv = 1.0f / fmaxf(sqrtf(g), 1e-12f);
    float tot = red[0][lane] + red[1][lane] + red[2][lane] + red[3][lane];
    out[o] = fmaxf(gsv * tot + b2[d], 0.0f);
  }
}

extern "C" void kernel_launch(void* const* d_in, const int* in_sizes, int n_in,
                              void* d_out, int out_size, void* d_ws, size_t ws_size,
                              hipStream_t stream){
  const float* X    = (const float*)d_in[0];
  const float* W1   = (const float*)d_in[1];
  const float* B1   = (const float*)d_in[2];
  const float* CW   = (const float*)d_in[3];
  const float* CB   = (const float*)d_in[4];
  const float* CENT = (const float*)d_in[5];
  const float* W2   = (const float*)d_in[6];
  const float* B2   = (const float*)d_in[7];
  float* out = (float*)d_out;
  char* ws = (char*)d_ws;

  ushort* W1b  = (ushort*)(ws + 0);            //  1,048,576
  ushort* CWb  = (ushort*)(ws + 1048576);      //     65,536 (pre-swizzled)
  float*  CBp  = (float*) (ws + 1114112);      //        512
  ushort* XNT  = (ushort*)(ws + 1114624);      // 16,777,216
  ushort* AThi = (ushort*)(ws + 17891840);     //  2,097,152
  ushort* ATlo = (ushort*)(ws + 19988992);     //  2,097,152
  ushort* VLb  = (ushort*)(ws + 22086144);     //  1,048,576
  float*  SSQ  = (float*) (ws + 23134720);     //      1,024
  float*  PART = (float*) (ws + 23135744);     //  8,388,608

  // prep: W1 cvt + conv_w cvt/pre-swizzle + conv_b pad
  prep<<<641, 256, 0, stream>>>(W1, CW, CB, W1b, CWb, CBp);
  // fused fc1 + norm -> XNT, then logits + softmax -> AThi/ATlo (XN eliminated)
  fc1sm<<<256, 512, 0, stream>>>(X, W1b, B1, CWb, CBp, XNT, AThi, ATlo);
  // VLAD via MFMA (a = hi+lo, asum via ones-MFMA) + intra-norm -> VLb + SSQ
  vlad_mfma<<<dim3(16, 4), 512, 0, stream>>>(AThi, ATlo, XNT, CENT, VLb, SSQ);
  // fc2: MFMA, dbuf staging, K-split 128 -> 1024 blocks (4/CU)
  fc2_mfma<<<dim3(8, 128), 256, 0, stream>>>(W2, VLb, PART);
  // final: gscale folded in; 4-way k-split + LDS reduce
  fin<<<256, 256, 0, stream>>>(PART, SSQ, B2, out);
}